// Round 6
// baseline (778.739 us; speedup 1.0000x reference)
//
#include <hip/hip_runtime.h>
#include <hip/hip_bf16.h>
#include <stdint.h>
#include <type_traits>

typedef __attribute__((ext_vector_type(8))) short bf16x8;
typedef __attribute__((ext_vector_type(4))) float f32x4;
typedef __attribute__((ext_vector_type(4))) int i32x4;

struct Scalars {
  double sum_wk;            // sum |Wk|
  double sum_wo;            // sum |Wo|
  unsigned int max_x_bits;  // max|x| as uint bits (nonneg float)
  unsigned int max_y_bits;  // max|x+retrieved| as uint bits
};

__device__ __forceinline__ unsigned short f2bf(float f) {
  __hip_bfloat16 h = __float2bfloat16(f);
  return *reinterpret_cast<unsigned short*>(&h);
}

// async global->LDS, 16B per lane; LDS dest is wave-uniform base + lane*16
__device__ __forceinline__ void async16(void* lds, const void* g) {
  __builtin_amdgcn_global_load_lds((__attribute__((address_space(1))) void*)g,
                                   (__attribute__((address_space(3))) void*)lds, 16, 0, 0);
}

// XCD-aware tile swizzle: consecutive blockIdx go round-robin to XCDs (bid%8);
// give each XCD a contiguous run of row-strips, col-blocks innermost.
__device__ __forceinline__ void tile_swizzle(int nxShift, int& bx, int& by) {
  const int per = gridDim.x >> 3;
  const int tile = (blockIdx.x & 7) * per + (blockIdx.x >> 3);
  bx = tile & ((1 << nxShift) - 1);
  by = tile >> nxShift;
}

// MFMA overloads: bf16 (K=32) and i8 (K=64), both 16B operands.
__device__ __forceinline__ f32x4 mm(bf16x8 a, bf16x8 b, f32x4 c) {
  return __builtin_amdgcn_mfma_f32_16x16x32_bf16(a, b, c, 0, 0, 0);
}
__device__ __forceinline__ i32x4 mm(i32x4 a, i32x4 b, i32x4 c) {
  return __builtin_amdgcn_mfma_i32_16x16x64_i8(a, b, c, 0, 0, 0);
}

// ---------------- stats: y=0 abssum(Wk), y=1 abssum(Wo), y=2 absmax(x) ----------
__global__ __launch_bounds__(256) void stats_kernel(const float* __restrict__ Wk,
                                                    const float* __restrict__ Wo,
                                                    const float* __restrict__ x,
                                                    Scalars* __restrict__ sc) {
  const int which = blockIdx.y;
  size_t tid = (size_t)blockIdx.x * 256 + threadIdx.x;
  size_t stride = (size_t)gridDim.x * 256;
  if (which < 2) {
    const float* w = which ? Wo : Wk;
    const size_t n = 1048576;
    double s = 0.0;
    for (size_t i = tid * 4; i < n; i += stride * 4) {
      float4 v = *(const float4*)(w + i);
      s += (double)fabsf(v.x) + (double)fabsf(v.y) + (double)fabsf(v.z) + (double)fabsf(v.w);
    }
#pragma unroll
    for (int o = 32; o > 0; o >>= 1) s += __shfl_xor(s, o);
    __shared__ double sm[4];
    if ((threadIdx.x & 63) == 0) sm[threadIdx.x >> 6] = s;
    __syncthreads();
    if (threadIdx.x == 0)
      atomicAdd(which ? &sc->sum_wo : &sc->sum_wk, sm[0] + sm[1] + sm[2] + sm[3]);
  } else {
    const size_t n = (size_t)32768 * 1024;
    float m = 0.0f;
    for (size_t i = tid * 4; i < n; i += stride * 4) {
      float4 v = *(const float4*)(x + i);
      m = fmaxf(m, fmaxf(fmaxf(fabsf(v.x), fabsf(v.y)), fmaxf(fabsf(v.z), fabsf(v.w))));
    }
#pragma unroll
    for (int o = 32; o > 0; o >>= 1) m = fmaxf(m, __shfl_xor(m, o));
    __shared__ float smf[4];
    if ((threadIdx.x & 63) == 0) smf[threadIdx.x >> 6] = m;
    __syncthreads();
    if (threadIdx.x == 0)
      atomicMax(&sc->max_x_bits,
                __float_as_uint(fmaxf(fmaxf(smf[0], smf[1]), fmaxf(smf[2], smf[3]))));
  }
}

// ---------------- prep: y=0 quantW(Wk), y=1 quantW(Wo), y=2 cast(mk),
//                  y=3 transpose(mv), y=4 quantAct(x) -------------------------
__global__ __launch_bounds__(256) void prep_kernel(
    const float* __restrict__ Wk, const float* __restrict__ Wo,
    const float* __restrict__ mk, const float* __restrict__ mv,
    const float* __restrict__ x, char* __restrict__ qWk8, char* __restrict__ qWo8,
    __hip_bfloat16* __restrict__ mkb, __hip_bfloat16* __restrict__ mvT,
    char* __restrict__ qx8, const Scalars* __restrict__ sc) {
  __shared__ float tl[32][33];
  const int which = blockIdx.y;
  const int t = threadIdx.x;
  size_t tid = (size_t)blockIdx.x * 256 + t;
  size_t stride = (size_t)gridDim.x * 256;
  if (which < 2) {
    const float* W = which ? Wo : Wk;
    char* q = which ? qWo8 : qWk8;
    const double sum = which ? sc->sum_wo : sc->sum_wk;
    const float thr = 0.5f * (float)(sum * (1.0 / 1048576.0));
    const size_t n = 1048576;
    for (size_t i = tid * 4; i < n; i += stride * 4) {
      float4 v = *(const float4*)(W + i);
      char4 o;
      o.x = (char)(fabsf(v.x) > thr ? (v.x > 0.f ? 1 : -1) : 0);
      o.y = (char)(fabsf(v.y) > thr ? (v.y > 0.f ? 1 : -1) : 0);
      o.z = (char)(fabsf(v.z) > thr ? (v.z > 0.f ? 1 : -1) : 0);
      o.w = (char)(fabsf(v.w) > thr ? (v.w > 0.f ? 1 : -1) : 0);
      *(char4*)(q + i) = o;
    }
  } else if (which == 2) {
    const size_t n = (size_t)2048 * 1024;
    for (size_t i = tid * 4; i < n; i += stride * 4) {
      float4 v = *(const float4*)(mk + i);
      ushort4 o;
      o.x = f2bf(v.x); o.y = f2bf(v.y); o.z = f2bf(v.z); o.w = f2bf(v.w);
      *(ushort4*)((unsigned short*)mkb + i) = o;
    }
  } else if (which == 3) {
    // mv [2048][1024] f32 -> mvT [1024][2048] bf16; blockIdx.x -> 32x32 tile
    const int ti = blockIdx.x & 31;  // e-block (1024/32)
    const int tj = blockIdx.x >> 5;  // m-block (2048/32)
    const int tx = t & 31, ty = t >> 5;
#pragma unroll
    for (int r = 0; r < 4; ++r)
      tl[ty + r * 8][tx] = mv[(size_t)(tj * 32 + ty + r * 8) * 1024 + ti * 32 + tx];
    __syncthreads();
#pragma unroll
    for (int r = 0; r < 4; ++r)
      mvT[(size_t)(ti * 32 + ty + r * 8) * 2048 + tj * 32 + tx] =
          __float2bfloat16(tl[tx][ty + r * 8]);
  } else {
    const float isc = __uint_as_float(sc->max_x_bits) / 127.0f;
    const size_t n = (size_t)32768 * 1024;
    for (size_t i = tid * 4; i < n; i += stride * 4) {
      float4 v = *(const float4*)(x + i);
      char4 o;
      o.x = (char)(int)fminf(fmaxf(rintf(v.x / isc), -128.f), 127.f);
      o.y = (char)(int)fminf(fmaxf(rintf(v.y / isc), -128.f), 127.f);
      o.z = (char)(int)fminf(fmaxf(rintf(v.z / isc), -128.f), 127.f);
      o.w = (char)(int)fminf(fmaxf(rintf(v.w / isc), -128.f), 127.f);
      *(char4*)(qx8 + i) = o;
    }
  }
}

__global__ __launch_bounds__(256) void quant_act_i8_kernel(const float* __restrict__ x,
                                                           char* __restrict__ q,
                                                           const unsigned int* __restrict__ maxbits,
                                                           size_t n) {
  const float isc = __uint_as_float(*maxbits) / 127.0f;
  size_t tid = (size_t)blockIdx.x * blockDim.x + threadIdx.x;
  size_t stride = (size_t)gridDim.x * blockDim.x;
  for (size_t i = tid * 4; i < n; i += stride * 4) {
    float4 v = *(const float4*)(x + i);
    char4 o;
    o.x = (char)(int)fminf(fmaxf(rintf(v.x / isc), -128.f), 127.f);
    o.y = (char)(int)fminf(fmaxf(rintf(v.y / isc), -128.f), 127.f);
    o.z = (char)(int)fminf(fmaxf(rintf(v.z / isc), -128.f), 127.f);
    o.w = (char)(int)fminf(fmaxf(rintf(v.w / isc), -128.f), 127.f);
    *(char4*)(q + i) = o;
  }
}

// ------- softmax, rows of 2048, in-place bf16; one wave per row (no LDS) -------
__global__ __launch_bounds__(256) void softmax_kernel(__hip_bfloat16* __restrict__ sims) {
  const int t = threadIdx.x, l = t & 63, wv = t >> 6;
  unsigned short* row = (unsigned short*)(sims + ((size_t)blockIdx.x * 4 + wv) * 2048);
  uint4 r4[4];
  float v[32];
#pragma unroll
  for (int c = 0; c < 4; ++c) r4[c] = *(const uint4*)(row + c * 512 + l * 8);
#pragma unroll
  for (int c = 0; c < 4; ++c) {
    unsigned u0 = r4[c].x, u1 = r4[c].y, u2 = r4[c].z, u3 = r4[c].w;
    v[c * 8 + 0] = __uint_as_float(u0 << 16); v[c * 8 + 1] = __uint_as_float(u0 & 0xffff0000u);
    v[c * 8 + 2] = __uint_as_float(u1 << 16); v[c * 8 + 3] = __uint_as_float(u1 & 0xffff0000u);
    v[c * 8 + 4] = __uint_as_float(u2 << 16); v[c * 8 + 5] = __uint_as_float(u2 & 0xffff0000u);
    v[c * 8 + 6] = __uint_as_float(u3 << 16); v[c * 8 + 7] = __uint_as_float(u3 & 0xffff0000u);
  }
  float m = v[0];
#pragma unroll
  for (int i = 1; i < 32; ++i) m = fmaxf(m, v[i]);
#pragma unroll
  for (int o = 32; o > 0; o >>= 1) m = fmaxf(m, __shfl_xor(m, o));
  float s = 0.f;
#pragma unroll
  for (int i = 0; i < 32; ++i) { v[i] = expf(v[i] - m); s += v[i]; }
#pragma unroll
  for (int o = 32; o > 0; o >>= 1) s += __shfl_xor(s, o);
#pragma unroll
  for (int c = 0; c < 4; ++c) {
    unsigned short b[8];
#pragma unroll
    for (int j = 0; j < 8; ++j) b[j] = f2bf(v[c * 8 + j] / s);
    uint4 o4;
    o4.x = (unsigned)b[0] | ((unsigned)b[1] << 16);
    o4.y = (unsigned)b[2] | ((unsigned)b[3] << 16);
    o4.z = (unsigned)b[4] | ((unsigned)b[5] << 16);
    o4.w = (unsigned)b[6] | ((unsigned)b[7] << 16);
    *(uint4*)(row + c * 512 + l * 8) = o4;
  }
}

// ---------------- unified 256x256 NT MFMA GEMM (R2-verbatim, best measured) ----
#define CFENCE() asm volatile("" ::: "memory")
#define BAR8() { CFENCE(); __builtin_amdgcn_s_barrier(); CFENCE(); }
#define WLGKM(N) { asm volatile("s_waitcnt lgkmcnt(" #N ")" ::: "memory"); __builtin_amdgcn_sched_barrier(0); }
#define WVM(N) asm volatile("s_waitcnt vmcnt(" #N ")" ::: "memory")

template <int EPI>
__global__ __launch_bounds__(512, 2) void gemm8(
    const char* __restrict__ A, const char* __restrict__ B, void* __restrict__ C,
    const float* __restrict__ aux, Scalars* __restrict__ sc,
    int Ndim, int KB, int nxShift) {
  constexpr bool I8 = (EPI >= 3);
  using FR  = typename std::conditional<I8, i32x4, bf16x8>::type;
  using ACC = typename std::conditional<I8, i32x4, f32x4>::type;
  __shared__ __align__(16) char lds[4][2][16384];  // [A0,A1,B0,B1][slot][16KiB]

  int bx, by;
  tile_swizzle(nxShift, bx, by);
  const int rowBlk = by * 256, colBlk = bx * 256;

  const int t = threadIdx.x, w = t >> 6, l = t & 63;
  const int wm = w >> 2, wn = w & 3;
  const int quad = l >> 4, m16 = l & 15;
  const int NT = KB >> 7, NIT = NT >> 1;

  int voA[2][2], voB[2][2];
#pragma unroll
  for (int hf = 0; hf < 2; ++hf)
#pragma unroll
    for (int j = 0; j < 2; ++j) {
      const int idx = j * 64 + (t >> 3);
      const int kby = ((t & 7) ^ (idx & 7)) << 4;
      voA[hf][j] = (rowBlk + ((idx >> 6) << 7) + (hf << 6) + (idx & 63)) * KB + kby;
      voB[hf][j] = (colBlk + ((idx >> 5) << 6) + (hf << 5) + (idx & 31)) * KB + kby;
    }

  const char* baA[2];
  const char* baB[2];
#pragma unroll
  for (int ks = 0; ks < 2; ++ks) {
    const int x16 = ((ks << 6) + (quad << 4)) ^ ((m16 & 7) << 4);
    baA[ks] = &lds[0][0][(wm * 64 + m16) * 128 + x16];
    baB[ks] = &lds[2][0][(wn * 32 + m16) * 128 + x16];
  }

#define STG_A(slot, hf, tk)                                                         \
  if ((tk) < NT) {                                                                  \
    _Pragma("unroll") for (int j = 0; j < 2; ++j)                                   \
      async16(&lds[hf][slot][j * 8192 + (w << 10)],                                 \
              A + (((size_t)(tk)) << 7) + voA[hf][j]);                              \
  }
#define STG_B(slot, hf, tk)                                                         \
  if ((tk) < NT) {                                                                  \
    _Pragma("unroll") for (int j = 0; j < 2; ++j)                                   \
      async16(&lds[2 + (hf)][slot][j * 8192 + (w << 10)],                           \
              B + (((size_t)(tk)) << 7) + voB[hf][j]);                              \
  }

#define LD_A(dst, slot, hf, f, ks) \
  dst = *(const FR*)(baA[ks] + ((hf)*32768 + (slot)*16384 + (f)*2048));
#define LD_B(dst, slot, hf, gg, ks) \
  dst = *(const FR*)(baB[ks] + ((hf)*32768 + (slot)*16384 + (gg)*2048));

#define R_A0(s) { _Pragma("unroll") for (int f_ = 0; f_ < 4; ++f_) { LD_A(af[f_][0], s, 0, f_, 0); LD_A(af[f_][1], s, 0, f_, 1); } }
#define R_A1(s) { _Pragma("unroll") for (int f_ = 0; f_ < 4; ++f_) { LD_A(af[f_][0], s, 1, f_, 0); LD_A(af[f_][1], s, 1, f_, 1); } }
#define R_B0(s) { _Pragma("unroll") for (int g_ = 0; g_ < 2; ++g_) { LD_B(b0[g_][0], s, 0, g_, 0); LD_B(b0[g_][1], s, 0, g_, 1); } }
#define R_B1(s) { _Pragma("unroll") for (int g_ = 0; g_ < 2; ++g_) { LD_B(b1[g_][0], s, 1, g_, 0); LD_B(b1[g_][1], s, 1, g_, 1); } }

#define MM8(FO, GO, BR)                                                             \
  __builtin_amdgcn_s_setprio(1);                                                    \
  _Pragma("unroll") for (int f_ = 0; f_ < 4; ++f_)                                  \
    _Pragma("unroll") for (int g_ = 0; g_ < 2; ++g_) {                              \
      acc[(FO) + f_][(GO) + g_] = mm(af[f_][0], BR[g_][0], acc[(FO) + f_][(GO) + g_]); \
      acc[(FO) + f_][(GO) + g_] = mm(af[f_][1], BR[g_][1], acc[(FO) + f_][(GO) + g_]); \
    }                                                                               \
  __builtin_amdgcn_s_setprio(0);

#define TSTEP(s, tk, last)                                                          \
  {                                                                                 \
    R_B1(s);                                                                        \
    STG_A((s) ^ 1, 1, (tk) + 1);                                                    \
    BAR8(); WLGKM(4);                                                               \
    MM8(0, 0, b0);                                                                  \
    BAR8();                                                                         \
    STG_A(s, 0, (tk) + 2);                                                          \
    BAR8(); WLGKM(0);                                                               \
    MM8(0, 2, b1);                                                                  \
    R_A1(s);                                                                        \
    BAR8();                                                                         \
    STG_B(s, 0, (tk) + 2);                                                          \
    BAR8(); WLGKM(0);                                                               \
    MM8(4, 0, b0);                                                                  \
    BAR8();                                                                         \
    STG_B(s, 1, (tk) + 2);                                                          \
    if (last) { WVM(0); } else { WVM(6); }                                          \
    BAR8();                                                                         \
    MM8(4, 2, b1);                                                                  \
    R_A0((s) ^ 1);                                                                  \
    R_B0((s) ^ 1);                                                                  \
  }

  FR af[4][2], b0[2][2], b1[2][2];
  ACC acc[8][4] = {};

  STG_A(0, 0, 0); STG_B(0, 0, 0); STG_B(0, 1, 0); STG_A(0, 1, 0);
  CFENCE();
  STG_A(1, 0, 1); STG_B(1, 0, 1); STG_B(1, 1, 1);
  WVM(6);
  BAR8();
  R_A0(0); R_B0(0);

  for (int it = 0; it < NIT; ++it) {
    const bool last = (it == NIT - 1);
    TSTEP(0, it * 2, last);
    TSTEP(1, it * 2 + 1, last);
  }

  float sK = 0.0f;
  if constexpr (EPI == 3)
    sK = (float)(sc->sum_wk * (1.0 / 1048576.0)) * (__uint_as_float(sc->max_x_bits) / 127.0f);
  if constexpr (EPI == 4)
    sK = (float)(sc->sum_wo * (1.0 / 1048576.0)) * (__uint_as_float(sc->max_y_bits) / 127.0f);

  float amax = 0.0f;
#pragma unroll
  for (int f = 0; f < 8; ++f) {
#pragma unroll
    for (int g = 0; g < 4; ++g) {
      const int col = colBlk + wn * 64 + g * 16 + m16;
#pragma unroll
      for (int rg = 0; rg < 4; ++rg) {
        const int row = rowBlk + wm * 128 + f * 16 + quad * 4 + rg;
        if constexpr (EPI == 1) {
          ((__hip_bfloat16*)C)[(size_t)row * Ndim + col] =
              __float2bfloat16(acc[f][g][rg] * 0.03125f);
        } else if constexpr (EPI == 2) {
          float v = acc[f][g][rg] + aux[(size_t)row * Ndim + col];
          ((float*)C)[(size_t)row * Ndim + col] = v;
          amax = fmaxf(amax, fabsf(v));
        } else if constexpr (EPI == 3) {
          ((__hip_bfloat16*)C)[(size_t)row * Ndim + col] =
              __float2bfloat16((float)acc[f][g][rg] * sK + aux[col]);
        } else {
          ((float*)C)[(size_t)row * Ndim + col] = (float)acc[f][g][rg] * sK + aux[col];
        }
      }
    }
  }

  if constexpr (EPI == 2) {
#pragma unroll
    for (int o = 32; o > 0; o >>= 1) amax = fmaxf(amax, __shfl_xor(amax, o));
    if (l == 0) atomicMax(&sc->max_y_bits, __float_as_uint(amax));
  }
#undef STG_A
#undef STG_B
#undef LD_A
#undef LD_B
#undef R_A0
#undef R_A1
#undef R_B0
#undef R_B1
#undef MM8
#undef TSTEP
}

// ------- 256x128 NT bf16 GEMM, BK=32, 48 KiB LDS -> 2 blocks/CU (experiment) ----
// C[m,n] = sum_k A[m,k]*B[n,k] + aux; f32 out + global absmax (EPI2 semantics).
// 512 threads = 8 waves (2M x 4N); per-wave output 128x32 (acc 8x2 frags = 64 VGPR).
// LDS [A0,A1,B][slot][8KiB]: A-half = 128 rows x 64B (rows with (g>>6)&1==hf),
// B = 128 rows x 64B. 16B chunks swizzled c_lds = c_glob ^ ((row>>1)&3)
// (pre-swizzled global source; read applies same XOR; <=2-way banks).
// Per K-tile: 2 MFMA phases (mh halves, 8 MFMA each), 3 barriers, one counted
// WVM(2) (stage units/tile = 3: A0,A1,B; 2 outstanding steady-state).
// Ledger: prologue issues t0{A0,B,A1}+t1{A0,B}=5, WVM(2) retires t0;
// step kt: p1 +A1(kt+1); mid +A0,B(kt+2), WVM(2) retires tile kt+1. last two
// steps drain with WVM(0).
__global__ __launch_bounds__(512, 2) void gemm2k(
    const char* __restrict__ A, const char* __restrict__ B, float* __restrict__ C,
    const float* __restrict__ aux, Scalars* __restrict__ sc,
    int Ndim, int KB, int nxShift) {
  __shared__ __align__(16) char lds[3][2][8192];  // [A0,A1,B][slot][8KiB]

  int bx, by;
  tile_swizzle(nxShift, bx, by);
  const int rowBlk = by * 256, colBlk = bx * 128;

  const int t = threadIdx.x, w = t >> 6, l = t & 63;
  const int wm = w >> 2, wn = w & 3;
  const int quad = l >> 4, m16 = l & 15;
  const int NT = KB >> 6;  // 64B rows per K-tile

  // staging: thread t covers region row r = t>>2, lds-chunk t&3,
  // global chunk (t&3)^((r>>1)&3); one async16 per region per thread.
  const int r = t >> 2;
  const int cg = ((t & 3) ^ ((r >> 1) & 3)) << 4;
  int voA[2];
  voA[0] = (rowBlk + ((r >> 6) << 7) + (r & 63)) * KB + cg;
  voA[1] = voA[0] + 64 * KB;
  const int voB = (colBlk + r) * KB + cg;

  // fragment reads: lane (m16,quad) reads 16B chunk quad of its row,
  // swizzled: c_lds = quad ^ ((m16>>1)&3) (region rows ≡ m16 mod 4 alignment).
  const int cofs = (quad ^ ((m16 >> 1) & 3)) << 4;
  const char* bA = &lds[0][0][0] + (wm * 64 + m16) * 64 + cofs;
  const char* bB = &lds[2][0][0] + (wn * 32 + m16) * 64 + cofs;

#define G2_STG_A(slot, hf, tk) \
  if ((tk) < NT) async16(&lds[hf][slot][t * 16], A + (((size_t)(tk)) << 6) + voA[hf]);
#define G2_STG_B(slot, tk) \
  if ((tk) < NT) async16(&lds[2][slot][t * 16], B + (((size_t)(tk)) << 6) + voB);
#define G2_LD_A(dst, slot, hf, f) \
  dst = *(const bf16x8*)(bA + ((hf) * 16384 + (slot) * 8192 + (f) * 1024));
#define G2_LD_B(dst, slot, g) \
  dst = *(const bf16x8*)(bB + ((slot) * 8192 + (g) * 1024));

#define G2_RA0(s) { _Pragma("unroll") for (int f_ = 0; f_ < 4; ++f_) G2_LD_A(af0[f_], s, 0, f_); }
#define G2_RA1(s) { _Pragma("unroll") for (int f_ = 0; f_ < 4; ++f_) G2_LD_A(af1[f_], s, 1, f_); }
#define G2_RB(s)  { _Pragma("unroll") for (int g_ = 0; g_ < 2; ++g_) G2_LD_B(b[g_], s, g_); }

#define G2_MM(MH, AF)                                                               \
  __builtin_amdgcn_s_setprio(1);                                                    \
  _Pragma("unroll") for (int f_ = 0; f_ < 4; ++f_)                                  \
    _Pragma("unroll") for (int g_ = 0; g_ < 2; ++g_)                                \
      acc[(MH) * 4 + f_][g_] = mm(AF[f_], b[g_], acc[(MH) * 4 + f_][g_]);           \
  __builtin_amdgcn_s_setprio(0);

// Entering: af0=A0(kt), b=B(kt) loaded; A1(kt) resident; 2 loads outstanding.
#define G2_TSTEP(s, kt, last)                                                       \
  {                                                                                 \
    G2_STG_A((s) ^ 1, 1, (kt) + 1);                                                 \
    BAR8(); WLGKM(0);                                                               \
    G2_MM(0, af0);                                                                  \
    G2_RA1(s);                                                                      \
    BAR8();                                                                         \
    G2_STG_A(s, 0, (kt) + 2); G2_STG_B(s, (kt) + 2);                                \
    if (last) { WVM(0); } else { WVM(2); }                                          \
    BAR8(); WLGKM(0);                                                               \
    G2_MM(1, af1);                                                                  \
    G2_RA0((s) ^ 1); G2_RB((s) ^ 1);                                                \
  }

  bf16x8 af0[4], af1[4], b[2];
  f32x4 acc[8][2] = {};

  // Prologue: t0{A0,B,A1} + t1{A0,B}; WVM(2) retires exactly tile0's 3 loads.
  G2_STG_A(0, 0, 0); G2_STG_B(0, 0); G2_STG_A(0, 1, 0);
  CFENCE();
  G2_STG_A(1, 0, 1); G2_STG_B(1, 1);
  WVM(2);
  BAR8();
  G2_RA0(0); G2_RB(0);

  for (int it = 0; it < NT / 2; ++it) {
    G2_TSTEP(0, it * 2, it * 2 >= NT - 2);
    G2_TSTEP(1, it * 2 + 1, it * 2 + 1 >= NT - 2);
  }

  // epilogue: f32(acc + aux) + global absmax
  float amax = 0.0f;
#pragma unroll
  for (int f = 0; f < 8; ++f) {
#pragma unroll
    for (int g = 0; g < 2; ++g) {
      const int col = colBlk + wn * 32 + g * 16 + m16;
#pragma unroll
      for (int rg = 0; rg < 4; ++rg) {
        const int row = rowBlk + wm * 128 + f * 16 + quad * 4 + rg;
        float v = acc[f][g][rg] + aux[(size_t)row * Ndim + col];
        C[(size_t)row * Ndim + col] = v;
        amax = fmaxf(amax, fabsf(v));
      }
    }
  }
#pragma unroll
  for (int o = 32; o > 0; o >>= 1) amax = fmaxf(amax, __shfl_xor(amax, o));
  if (l == 0) atomicMax(&sc->max_y_bits, __float_as_uint(amax));
#undef G2_STG_A
#undef G2_STG_B
#undef G2_LD_A
#undef G2_LD_B
#undef G2_RA0
#undef G2_RA1
#undef G2_RB
#undef G2_MM
#undef G2_TSTEP
}

extern "C" void kernel_launch(void* const* d_in, const int* in_sizes, int n_in,
                              void* d_out, int out_size, void* d_ws, size_t ws_size,
                              hipStream_t stream) {
  (void)in_sizes; (void)n_in; (void)out_size; (void)ws_size;
  const float* x  = (const float*)d_in[0];   // [8,4096,1024]
  const float* mk = (const float*)d_in[1];   // [2048,1024]
  const float* mv = (const float*)d_in[2];   // [2048,1024]
  const float* Wk = (const float*)d_in[3];   // [1024,1024]
  const float* bk = (const float*)d_in[4];   // [1024]
  // d_in[5], d_in[6] = Wv, bv -> dead w.r.t. output; skipped.
  const float* Wo = (const float*)d_in[7];
  const float* bo = (const float*)d_in[8];
  float* out = (float*)d_out;

  const int M = 32768, E = 1024, MEM = 2048;

  char* ws = (char*)d_ws;
  Scalars* sc = (Scalars*)ws;
  const size_t off0 = 256;
  char* qx8 = ws + off0;                                            // 32 MB
  __hip_bfloat16* qk = (__hip_bfloat16*)(ws + off0 + (size_t)M * E); // 64 MB
  float* y = (float*)(ws + off0);                                   // reuses qx8+qk region (128 MB)
  const size_t off1 = off0 + (size_t)M * E * 4;
  __hip_bfloat16* sims = (__hip_bfloat16*)(ws + off1);              // 128 MB
  char* qy8 = (char*)sims;                                          // reuses sims (32 MB)
  const size_t off2 = off1 + (size_t)M * MEM * 2;
  char* qWk8 = ws + off2;                                           // 1 MB
  char* qWo8 = qWk8 + (size_t)E * E;                                // 1 MB
  __hip_bfloat16* mkb = (__hip_bfloat16*)(qWo8 + (size_t)E * E);    // 4 MB
  __hip_bfloat16* mvT = mkb + (size_t)MEM * E;                      // 4 MB

  hipMemsetAsync(ws, 0, 256, stream);

  // stats: abssum(Wk), abssum(Wo), absmax(x) in one launch
  stats_kernel<<<dim3(1024, 3), dim3(256), 0, stream>>>(Wk, Wo, x, sc);
  // prep: quantW(Wk), quantW(Wo), cast(mk), transpose(mv), quantAct(x)
  prep_kernel<<<dim3(2048, 5), dim3(256), 0, stream>>>(Wk, Wo, mk, mv, x, qWk8, qWo8,
                                                       mkb, mvT, qx8, sc);

  // qk = bf16((qx @ qWk^T) * s_k + bk)      [i8, KB=1024]
  gemm8<3><<<dim3((E / 256) * (M / 256)), dim3(512), 0, stream>>>(
      qx8, qWk8, qk, bk, sc, E, E, 2);
  // sims = bf16((qk @ mk^T) / 32)           [bf16, KB=2048, 1 block/CU]
  gemm8<1><<<dim3((MEM / 256) * (M / 256)), dim3(512), 0, stream>>>(
      (const char*)qk, (const char*)mkb, sims, nullptr, sc, MEM, 2 * E, 3);
  // softmax rows (in place), one wave per row
  softmax_kernel<<<dim3(M / 4), dim3(256), 0, stream>>>(sims);
  // y = probs @ mv + x (+ global max|y|)    [bf16, KB=4096, 2 blocks/CU A/B test]
  gemm2k<<<dim3((E / 128) * (M / 256)), dim3(512), 0, stream>>>(
      (const char*)sims, (const char*)mvT, y, x, sc, E, 2 * MEM, 3);
  // qy = quant(y)
  quant_act_i8_kernel<<<dim3(2048), dim3(256), 0, stream>>>(y, qy8, &sc->max_y_bits, (size_t)M * E);
  // out = (qy @ qWo^T) * s_o + bo           [i8, KB=1024]
  gemm8<4><<<dim3((E / 256) * (M / 256)), dim3(512), 0, stream>>>(
      qy8, qWo8, out, bo, sc, E, E, 2);
}

// Round 7
// 760.927 us; speedup vs baseline: 1.0234x; 1.0234x over previous
//
#include <hip/hip_runtime.h>
#include <hip/hip_bf16.h>
#include <stdint.h>
#include <type_traits>

typedef __attribute__((ext_vector_type(8))) short bf16x8;
typedef __attribute__((ext_vector_type(4))) float f32x4;
typedef __attribute__((ext_vector_type(4))) int i32x4;

struct Scalars {
  double sum_wk;            // sum |Wk|
  double sum_wo;            // sum |Wo|
  unsigned int max_x_bits;  // max|x| as uint bits (nonneg float)
  unsigned int max_y_bits;  // max|x+retrieved| as uint bits
};

__device__ __forceinline__ unsigned short f2bf(float f) {
  __hip_bfloat16 h = __float2bfloat16(f);
  return *reinterpret_cast<unsigned short*>(&h);
}

// async global->LDS, 16B per lane; LDS dest is wave-uniform base + lane*16
__device__ __forceinline__ void async16(void* lds, const void* g) {
  __builtin_amdgcn_global_load_lds((__attribute__((address_space(1))) void*)g,
                                   (__attribute__((address_space(3))) void*)lds, 16, 0, 0);
}

// XCD-aware tile swizzle: consecutive blockIdx go round-robin to XCDs (bid%8);
// give each XCD a contiguous run of row-strips, col-blocks innermost.
__device__ __forceinline__ void tile_swizzle(int nxShift, int& bx, int& by) {
  const int per = gridDim.x >> 3;
  const int tile = (blockIdx.x & 7) * per + (blockIdx.x >> 3);
  bx = tile & ((1 << nxShift) - 1);
  by = tile >> nxShift;
}

// MFMA overloads: bf16 (K=32) and i8 (K=64), both 16B operands.
__device__ __forceinline__ f32x4 mm(bf16x8 a, bf16x8 b, f32x4 c) {
  return __builtin_amdgcn_mfma_f32_16x16x32_bf16(a, b, c, 0, 0, 0);
}
__device__ __forceinline__ i32x4 mm(i32x4 a, i32x4 b, i32x4 c) {
  return __builtin_amdgcn_mfma_i32_16x16x64_i8(a, b, c, 0, 0, 0);
}

// ---------------- stats: y=0 abssum(Wk), y=1 abssum(Wo), y=2 absmax(x) ----------
__global__ __launch_bounds__(256) void stats_kernel(const float* __restrict__ Wk,
                                                    const float* __restrict__ Wo,
                                                    const float* __restrict__ x,
                                                    Scalars* __restrict__ sc) {
  const int which = blockIdx.y;
  size_t tid = (size_t)blockIdx.x * 256 + threadIdx.x;
  size_t stride = (size_t)gridDim.x * 256;
  if (which < 2) {
    const float* w = which ? Wo : Wk;
    const size_t n = 1048576;
    double s = 0.0;
    for (size_t i = tid * 4; i < n; i += stride * 4) {
      float4 v = *(const float4*)(w + i);
      s += (double)fabsf(v.x) + (double)fabsf(v.y) + (double)fabsf(v.z) + (double)fabsf(v.w);
    }
#pragma unroll
    for (int o = 32; o > 0; o >>= 1) s += __shfl_xor(s, o);
    __shared__ double sm[4];
    if ((threadIdx.x & 63) == 0) sm[threadIdx.x >> 6] = s;
    __syncthreads();
    if (threadIdx.x == 0)
      atomicAdd(which ? &sc->sum_wo : &sc->sum_wk, sm[0] + sm[1] + sm[2] + sm[3]);
  } else {
    const size_t n = (size_t)32768 * 1024;
    float m = 0.0f;
    for (size_t i = tid * 4; i < n; i += stride * 4) {
      float4 v = *(const float4*)(x + i);
      m = fmaxf(m, fmaxf(fmaxf(fabsf(v.x), fabsf(v.y)), fmaxf(fabsf(v.z), fabsf(v.w))));
    }
#pragma unroll
    for (int o = 32; o > 0; o >>= 1) m = fmaxf(m, __shfl_xor(m, o));
    __shared__ float smf[4];
    if ((threadIdx.x & 63) == 0) smf[threadIdx.x >> 6] = m;
    __syncthreads();
    if (threadIdx.x == 0)
      atomicMax(&sc->max_x_bits,
                __float_as_uint(fmaxf(fmaxf(smf[0], smf[1]), fmaxf(smf[2], smf[3]))));
  }
}

// ---------------- prep: y=0 quantW(Wk), y=1 quantW(Wo), y=2 cast(mk),
//                  y=3 transpose(mv), y=4 quantAct(x) -------------------------
__global__ __launch_bounds__(256) void prep_kernel(
    const float* __restrict__ Wk, const float* __restrict__ Wo,
    const float* __restrict__ mk, const float* __restrict__ mv,
    const float* __restrict__ x, char* __restrict__ qWk8, char* __restrict__ qWo8,
    __hip_bfloat16* __restrict__ mkb, __hip_bfloat16* __restrict__ mvT,
    char* __restrict__ qx8, const Scalars* __restrict__ sc) {
  __shared__ float tl[32][33];
  const int which = blockIdx.y;
  const int t = threadIdx.x;
  size_t tid = (size_t)blockIdx.x * 256 + t;
  size_t stride = (size_t)gridDim.x * 256;
  if (which < 2) {
    const float* W = which ? Wo : Wk;
    char* q = which ? qWo8 : qWk8;
    const double sum = which ? sc->sum_wo : sc->sum_wk;
    const float thr = 0.5f * (float)(sum * (1.0 / 1048576.0));
    const size_t n = 1048576;
    for (size_t i = tid * 4; i < n; i += stride * 4) {
      float4 v = *(const float4*)(W + i);
      char4 o;
      o.x = (char)(fabsf(v.x) > thr ? (v.x > 0.f ? 1 : -1) : 0);
      o.y = (char)(fabsf(v.y) > thr ? (v.y > 0.f ? 1 : -1) : 0);
      o.z = (char)(fabsf(v.z) > thr ? (v.z > 0.f ? 1 : -1) : 0);
      o.w = (char)(fabsf(v.w) > thr ? (v.w > 0.f ? 1 : -1) : 0);
      *(char4*)(q + i) = o;
    }
  } else if (which == 2) {
    const size_t n = (size_t)2048 * 1024;
    for (size_t i = tid * 4; i < n; i += stride * 4) {
      float4 v = *(const float4*)(mk + i);
      ushort4 o;
      o.x = f2bf(v.x); o.y = f2bf(v.y); o.z = f2bf(v.z); o.w = f2bf(v.w);
      *(ushort4*)((unsigned short*)mkb + i) = o;
    }
  } else if (which == 3) {
    // mv [2048][1024] f32 -> mvT [1024][2048] bf16; blockIdx.x -> 32x32 tile
    const int ti = blockIdx.x & 31;  // e-block (1024/32)
    const int tj = blockIdx.x >> 5;  // m-block (2048/32)
    const int tx = t & 31, ty = t >> 5;
#pragma unroll
    for (int r = 0; r < 4; ++r)
      tl[ty + r * 8][tx] = mv[(size_t)(tj * 32 + ty + r * 8) * 1024 + ti * 32 + tx];
    __syncthreads();
#pragma unroll
    for (int r = 0; r < 4; ++r)
      mvT[(size_t)(ti * 32 + ty + r * 8) * 2048 + tj * 32 + tx] =
          __float2bfloat16(tl[tx][ty + r * 8]);
  } else {
    const float isc = __uint_as_float(sc->max_x_bits) / 127.0f;
    const size_t n = (size_t)32768 * 1024;
    for (size_t i = tid * 4; i < n; i += stride * 4) {
      float4 v = *(const float4*)(x + i);
      char4 o;
      o.x = (char)(int)fminf(fmaxf(rintf(v.x / isc), -128.f), 127.f);
      o.y = (char)(int)fminf(fmaxf(rintf(v.y / isc), -128.f), 127.f);
      o.z = (char)(int)fminf(fmaxf(rintf(v.z / isc), -128.f), 127.f);
      o.w = (char)(int)fminf(fmaxf(rintf(v.w / isc), -128.f), 127.f);
      *(char4*)(qx8 + i) = o;
    }
  }
}

// ------- quantize y (bf16 storage) -> i8; isc from exact f32 absmax ------------
__global__ __launch_bounds__(256) void quant_act_bf16_kernel(
    const __hip_bfloat16* __restrict__ y, char* __restrict__ q,
    const unsigned int* __restrict__ maxbits, size_t n) {
  const float isc = __uint_as_float(*maxbits) / 127.0f;
  size_t tid = (size_t)blockIdx.x * blockDim.x + threadIdx.x;
  size_t stride = (size_t)gridDim.x * blockDim.x;
  for (size_t i = tid * 8; i < n; i += stride * 8) {
    uint4 r = *(const uint4*)((const unsigned short*)y + i);
    float v[8];
    v[0] = __uint_as_float(r.x << 16); v[1] = __uint_as_float(r.x & 0xffff0000u);
    v[2] = __uint_as_float(r.y << 16); v[3] = __uint_as_float(r.y & 0xffff0000u);
    v[4] = __uint_as_float(r.z << 16); v[5] = __uint_as_float(r.z & 0xffff0000u);
    v[6] = __uint_as_float(r.w << 16); v[7] = __uint_as_float(r.w & 0xffff0000u);
    char o[8];
#pragma unroll
    for (int j = 0; j < 8; ++j)
      o[j] = (char)(int)fminf(fmaxf(rintf(v[j] / isc), -128.f), 127.f);
    uint2 pk;
    pk.x = (unsigned char)o[0] | ((unsigned)(unsigned char)o[1] << 8) |
           ((unsigned)(unsigned char)o[2] << 16) | ((unsigned)(unsigned char)o[3] << 24);
    pk.y = (unsigned char)o[4] | ((unsigned)(unsigned char)o[5] << 8) |
           ((unsigned)(unsigned char)o[6] << 16) | ((unsigned)(unsigned char)o[7] << 24);
    *(uint2*)(q + i) = pk;
  }
}

// ------- softmax, rows of 2048, in-place bf16; one wave per row (no LDS) -------
__global__ __launch_bounds__(256) void softmax_kernel(__hip_bfloat16* __restrict__ sims) {
  const int t = threadIdx.x, l = t & 63, wv = t >> 6;
  unsigned short* row = (unsigned short*)(sims + ((size_t)blockIdx.x * 4 + wv) * 2048);
  uint4 r4[4];
  float v[32];
#pragma unroll
  for (int c = 0; c < 4; ++c) r4[c] = *(const uint4*)(row + c * 512 + l * 8);
#pragma unroll
  for (int c = 0; c < 4; ++c) {
    unsigned u0 = r4[c].x, u1 = r4[c].y, u2 = r4[c].z, u3 = r4[c].w;
    v[c * 8 + 0] = __uint_as_float(u0 << 16); v[c * 8 + 1] = __uint_as_float(u0 & 0xffff0000u);
    v[c * 8 + 2] = __uint_as_float(u1 << 16); v[c * 8 + 3] = __uint_as_float(u1 & 0xffff0000u);
    v[c * 8 + 4] = __uint_as_float(u2 << 16); v[c * 8 + 5] = __uint_as_float(u2 & 0xffff0000u);
    v[c * 8 + 6] = __uint_as_float(u3 << 16); v[c * 8 + 7] = __uint_as_float(u3 & 0xffff0000u);
  }
  float m = v[0];
#pragma unroll
  for (int i = 1; i < 32; ++i) m = fmaxf(m, v[i]);
#pragma unroll
  for (int o = 32; o > 0; o >>= 1) m = fmaxf(m, __shfl_xor(m, o));
  float s = 0.f;
#pragma unroll
  for (int i = 0; i < 32; ++i) { v[i] = expf(v[i] - m); s += v[i]; }
#pragma unroll
  for (int o = 32; o > 0; o >>= 1) s += __shfl_xor(s, o);
#pragma unroll
  for (int c = 0; c < 4; ++c) {
    unsigned short b[8];
#pragma unroll
    for (int j = 0; j < 8; ++j) b[j] = f2bf(v[c * 8 + j] / s);
    uint4 o4;
    o4.x = (unsigned)b[0] | ((unsigned)b[1] << 16);
    o4.y = (unsigned)b[2] | ((unsigned)b[3] << 16);
    o4.z = (unsigned)b[4] | ((unsigned)b[5] << 16);
    o4.w = (unsigned)b[6] | ((unsigned)b[7] << 16);
    *(uint4*)(row + c * 512 + l * 8) = o4;
  }
}

// ---------------- unified 256x256 NT MFMA GEMM (R2-verbatim, best measured) ----
// C[m,n] = sum_k A[m,k]*B[n,k], 128-byte K-tiles (bf16 BK=64 elems / i8 BK=128).
// 512 threads = 8 waves (2M x 4N); per-wave output 128x64.
// EPI: 1=bf16(acc/32)  2=bf16(acc+aux) + f32 absmax (y path)
//      3=bf16(acc*sK+aux[col])  4=f32(acc*sO+aux[col]).
#define CFENCE() asm volatile("" ::: "memory")
#define BAR8() { CFENCE(); __builtin_amdgcn_s_barrier(); CFENCE(); }
#define WLGKM(N) { asm volatile("s_waitcnt lgkmcnt(" #N ")" ::: "memory"); __builtin_amdgcn_sched_barrier(0); }
#define WVM(N) asm volatile("s_waitcnt vmcnt(" #N ")" ::: "memory")

template <int EPI>
__global__ __launch_bounds__(512, 2) void gemm8(
    const char* __restrict__ A, const char* __restrict__ B, void* __restrict__ C,
    const float* __restrict__ aux, Scalars* __restrict__ sc,
    int Ndim, int KB, int nxShift) {
  constexpr bool I8 = (EPI >= 3);
  using FR  = typename std::conditional<I8, i32x4, bf16x8>::type;
  using ACC = typename std::conditional<I8, i32x4, f32x4>::type;
  __shared__ __align__(16) char lds[4][2][16384];  // [A0,A1,B0,B1][slot][16KiB]

  int bx, by;
  tile_swizzle(nxShift, bx, by);
  const int rowBlk = by * 256, colBlk = bx * 256;

  const int t = threadIdx.x, w = t >> 6, l = t & 63;
  const int wm = w >> 2, wn = w & 3;
  const int quad = l >> 4, m16 = l & 15;
  const int NT = KB >> 7, NIT = NT >> 1;

  int voA[2][2], voB[2][2];
#pragma unroll
  for (int hf = 0; hf < 2; ++hf)
#pragma unroll
    for (int j = 0; j < 2; ++j) {
      const int idx = j * 64 + (t >> 3);
      const int kby = ((t & 7) ^ (idx & 7)) << 4;
      voA[hf][j] = (rowBlk + ((idx >> 6) << 7) + (hf << 6) + (idx & 63)) * KB + kby;
      voB[hf][j] = (colBlk + ((idx >> 5) << 6) + (hf << 5) + (idx & 31)) * KB + kby;
    }

  const char* baA[2];
  const char* baB[2];
#pragma unroll
  for (int ks = 0; ks < 2; ++ks) {
    const int x16 = ((ks << 6) + (quad << 4)) ^ ((m16 & 7) << 4);
    baA[ks] = &lds[0][0][(wm * 64 + m16) * 128 + x16];
    baB[ks] = &lds[2][0][(wn * 32 + m16) * 128 + x16];
  }

#define STG_A(slot, hf, tk)                                                         \
  if ((tk) < NT) {                                                                  \
    _Pragma("unroll") for (int j = 0; j < 2; ++j)                                   \
      async16(&lds[hf][slot][j * 8192 + (w << 10)],                                 \
              A + (((size_t)(tk)) << 7) + voA[hf][j]);                              \
  }
#define STG_B(slot, hf, tk)                                                         \
  if ((tk) < NT) {                                                                  \
    _Pragma("unroll") for (int j = 0; j < 2; ++j)                                   \
      async16(&lds[2 + (hf)][slot][j * 8192 + (w << 10)],                           \
              B + (((size_t)(tk)) << 7) + voB[hf][j]);                              \
  }

#define LD_A(dst, slot, hf, f, ks) \
  dst = *(const FR*)(baA[ks] + ((hf)*32768 + (slot)*16384 + (f)*2048));
#define LD_B(dst, slot, hf, gg, ks) \
  dst = *(const FR*)(baB[ks] + ((hf)*32768 + (slot)*16384 + (gg)*2048));

#define R_A0(s) { _Pragma("unroll") for (int f_ = 0; f_ < 4; ++f_) { LD_A(af[f_][0], s, 0, f_, 0); LD_A(af[f_][1], s, 0, f_, 1); } }
#define R_A1(s) { _Pragma("unroll") for (int f_ = 0; f_ < 4; ++f_) { LD_A(af[f_][0], s, 1, f_, 0); LD_A(af[f_][1], s, 1, f_, 1); } }
#define R_B0(s) { _Pragma("unroll") for (int g_ = 0; g_ < 2; ++g_) { LD_B(b0[g_][0], s, 0, g_, 0); LD_B(b0[g_][1], s, 0, g_, 1); } }
#define R_B1(s) { _Pragma("unroll") for (int g_ = 0; g_ < 2; ++g_) { LD_B(b1[g_][0], s, 1, g_, 0); LD_B(b1[g_][1], s, 1, g_, 1); } }

#define MM8(FO, GO, BR)                                                             \
  __builtin_amdgcn_s_setprio(1);                                                    \
  _Pragma("unroll") for (int f_ = 0; f_ < 4; ++f_)                                  \
    _Pragma("unroll") for (int g_ = 0; g_ < 2; ++g_) {                              \
      acc[(FO) + f_][(GO) + g_] = mm(af[f_][0], BR[g_][0], acc[(FO) + f_][(GO) + g_]); \
      acc[(FO) + f_][(GO) + g_] = mm(af[f_][1], BR[g_][1], acc[(FO) + f_][(GO) + g_]); \
    }                                                                               \
  __builtin_amdgcn_s_setprio(0);

#define TSTEP(s, tk, last)                                                          \
  {                                                                                 \
    R_B1(s);                                                                        \
    STG_A((s) ^ 1, 1, (tk) + 1);                                                    \
    BAR8(); WLGKM(4);                                                               \
    MM8(0, 0, b0);                                                                  \
    BAR8();                                                                         \
    STG_A(s, 0, (tk) + 2);                                                          \
    BAR8(); WLGKM(0);                                                               \
    MM8(0, 2, b1);                                                                  \
    R_A1(s);                                                                        \
    BAR8();                                                                         \
    STG_B(s, 0, (tk) + 2);                                                          \
    BAR8(); WLGKM(0);                                                               \
    MM8(4, 0, b0);                                                                  \
    BAR8();                                                                         \
    STG_B(s, 1, (tk) + 2);                                                          \
    if (last) { WVM(0); } else { WVM(6); }                                          \
    BAR8();                                                                         \
    MM8(4, 2, b1);                                                                  \
    R_A0((s) ^ 1);                                                                  \
    R_B0((s) ^ 1);                                                                  \
  }

  FR af[4][2], b0[2][2], b1[2][2];
  ACC acc[8][4] = {};

  STG_A(0, 0, 0); STG_B(0, 0, 0); STG_B(0, 1, 0); STG_A(0, 1, 0);
  CFENCE();
  STG_A(1, 0, 1); STG_B(1, 0, 1); STG_B(1, 1, 1);
  WVM(6);
  BAR8();
  R_A0(0); R_B0(0);

  for (int it = 0; it < NIT; ++it) {
    const bool last = (it == NIT - 1);
    TSTEP(0, it * 2, last);
    TSTEP(1, it * 2 + 1, last);
  }

  float sK = 0.0f;
  if constexpr (EPI == 3)
    sK = (float)(sc->sum_wk * (1.0 / 1048576.0)) * (__uint_as_float(sc->max_x_bits) / 127.0f);
  if constexpr (EPI == 4)
    sK = (float)(sc->sum_wo * (1.0 / 1048576.0)) * (__uint_as_float(sc->max_y_bits) / 127.0f);

  float amax = 0.0f;
#pragma unroll
  for (int f = 0; f < 8; ++f) {
#pragma unroll
    for (int g = 0; g < 4; ++g) {
      const int col = colBlk + wn * 64 + g * 16 + m16;
#pragma unroll
      for (int rg = 0; rg < 4; ++rg) {
        const int row = rowBlk + wm * 128 + f * 16 + quad * 4 + rg;
        if constexpr (EPI == 1) {
          ((__hip_bfloat16*)C)[(size_t)row * Ndim + col] =
              __float2bfloat16(acc[f][g][rg] * 0.03125f);
        } else if constexpr (EPI == 2) {
          // y stored bf16; absmax from exact f32 (isc has no systematic shift)
          float v = acc[f][g][rg] + aux[(size_t)row * Ndim + col];
          ((__hip_bfloat16*)C)[(size_t)row * Ndim + col] = __float2bfloat16(v);
          amax = fmaxf(amax, fabsf(v));
        } else if constexpr (EPI == 3) {
          ((__hip_bfloat16*)C)[(size_t)row * Ndim + col] =
              __float2bfloat16((float)acc[f][g][rg] * sK + aux[col]);
        } else {
          ((float*)C)[(size_t)row * Ndim + col] = (float)acc[f][g][rg] * sK + aux[col];
        }
      }
    }
  }

  if constexpr (EPI == 2) {
#pragma unroll
    for (int o = 32; o > 0; o >>= 1) amax = fmaxf(amax, __shfl_xor(amax, o));
    if (l == 0) atomicMax(&sc->max_y_bits, __float_as_uint(amax));
  }
#undef STG_A
#undef STG_B
#undef LD_A
#undef LD_B
#undef R_A0
#undef R_A1
#undef R_B0
#undef R_B1
#undef MM8
#undef TSTEP
}

extern "C" void kernel_launch(void* const* d_in, const int* in_sizes, int n_in,
                              void* d_out, int out_size, void* d_ws, size_t ws_size,
                              hipStream_t stream) {
  (void)in_sizes; (void)n_in; (void)out_size; (void)ws_size;
  const float* x  = (const float*)d_in[0];   // [8,4096,1024]
  const float* mk = (const float*)d_in[1];   // [2048,1024]
  const float* mv = (const float*)d_in[2];   // [2048,1024]
  const float* Wk = (const float*)d_in[3];   // [1024,1024]
  const float* bk = (const float*)d_in[4];   // [1024]
  // d_in[5], d_in[6] = Wv, bv -> dead w.r.t. output; skipped.
  const float* Wo = (const float*)d_in[7];
  const float* bo = (const float*)d_in[8];
  float* out = (float*)d_out;

  const int M = 32768, E = 1024, MEM = 2048;

  char* ws = (char*)d_ws;
  Scalars* sc = (Scalars*)ws;
  const size_t off0 = 256;
  char* qx8 = ws + off0;                                              // 32 MB
  __hip_bfloat16* qk = (__hip_bfloat16*)(ws + off0 + (size_t)M * E);  // 64 MB
  __hip_bfloat16* yb = (__hip_bfloat16*)(ws + off0);                  // 64 MB (reuses qx8+qk)
  const size_t off1 = off0 + (size_t)M * E * 4;
  __hip_bfloat16* sims = (__hip_bfloat16*)(ws + off1);                // 128 MB
  char* qy8 = (char*)sims;                                            // reuses sims (32 MB)
  const size_t off2 = off1 + (size_t)M * MEM * 2;
  char* qWk8 = ws + off2;                                             // 1 MB
  char* qWo8 = qWk8 + (size_t)E * E;                                  // 1 MB
  __hip_bfloat16* mkb = (__hip_bfloat16*)(qWo8 + (size_t)E * E);      // 4 MB
  __hip_bfloat16* mvT = mkb + (size_t)MEM * E;                        // 4 MB

  hipMemsetAsync(ws, 0, 256, stream);

  // stats: abssum(Wk), abssum(Wo), absmax(x) in one launch
  stats_kernel<<<dim3(1024, 3), dim3(256), 0, stream>>>(Wk, Wo, x, sc);
  // prep: quantW(Wk), quantW(Wo), cast(mk), transpose(mv), quantAct(x)
  prep_kernel<<<dim3(2048, 5), dim3(256), 0, stream>>>(Wk, Wo, mk, mv, x, qWk8, qWo8,
                                                       mkb, mvT, qx8, sc);

  // qk = bf16((qx @ qWk^T) * s_k + bk)      [i8, KB=1024]
  gemm8<3><<<dim3((E / 256) * (M / 256)), dim3(512), 0, stream>>>(
      qx8, qWk8, qk, bk, sc, E, E, 2);
  // sims = bf16((qk @ mk^T) / 32)           [bf16, KB=2048]
  gemm8<1><<<dim3((MEM / 256) * (M / 256)), dim3(512), 0, stream>>>(
      (const char*)qk, (const char*)mkb, sims, nullptr, sc, MEM, 2 * E, 3);
  // softmax rows (in place), one wave per row
  softmax_kernel<<<dim3(M / 4), dim3(256), 0, stream>>>(sims);
  // y = probs @ mv + x (+ global max|y| from exact f32)  [bf16, KB=4096]
  gemm8<2><<<dim3((E / 256) * (M / 256)), dim3(512), 0, stream>>>(
      (const char*)sims, (const char*)mvT, yb, x, sc, E, 2 * MEM, 2);
  // qy = quant(y)  (y read as bf16)
  quant_act_bf16_kernel<<<dim3(2048), dim3(256), 0, stream>>>(yb, qy8, &sc->max_y_bits,
                                                              (size_t)M * E);
  // out = (qy @ qWo^T) * s_o + bo           [i8, KB=1024]
  gemm8<4><<<dim3((E / 256) * (M / 256)), dim3(512), 0, stream>>>(
      qy8, qWo8, out, bo, sc, E, E, 2);
}

// Round 8
// 737.709 us; speedup vs baseline: 1.0556x; 1.0315x over previous
//
#include <hip/hip_runtime.h>
#include <hip/hip_bf16.h>
#include <stdint.h>
#include <type_traits>

typedef __attribute__((ext_vector_type(8))) short bf16x8;
typedef __attribute__((ext_vector_type(4))) float f32x4;
typedef __attribute__((ext_vector_type(4))) int i32x4;

struct Scalars {
  double sum_wk;            // sum |Wk|
  double sum_wo;            // sum |Wo|
  unsigned int max_x_bits;  // max|x| as uint bits (nonneg float)
  unsigned int max_y_bits;  // max|x+retrieved| as uint bits
};

__device__ __forceinline__ unsigned short f2bf(float f) {
  __hip_bfloat16 h = __float2bfloat16(f);
  return *reinterpret_cast<unsigned short*>(&h);
}

// async global->LDS, 16B per lane; LDS dest is wave-uniform base + lane*16
__device__ __forceinline__ void async16(void* lds, const void* g) {
  __builtin_amdgcn_global_load_lds((__attribute__((address_space(1))) void*)g,
                                   (__attribute__((address_space(3))) void*)lds, 16, 0, 0);
}

// XCD-aware tile swizzle: consecutive blockIdx go round-robin to XCDs (bid%8);
// give each XCD a contiguous run of row-strips, col-blocks innermost.
__device__ __forceinline__ void tile_swizzle(int nxShift, int& bx, int& by) {
  const int per = gridDim.x >> 3;
  const int tile = (blockIdx.x & 7) * per + (blockIdx.x >> 3);
  bx = tile & ((1 << nxShift) - 1);
  by = tile >> nxShift;
}

// MFMA overloads: bf16 (K=32) and i8 (K=64), both 16B operands.
__device__ __forceinline__ f32x4 mm(bf16x8 a, bf16x8 b, f32x4 c) {
  return __builtin_amdgcn_mfma_f32_16x16x32_bf16(a, b, c, 0, 0, 0);
}
__device__ __forceinline__ i32x4 mm(i32x4 a, i32x4 b, i32x4 c) {
  return __builtin_amdgcn_mfma_i32_16x16x64_i8(a, b, c, 0, 0, 0);
}

// ---- stats: y=0 abssum(Wk), y=1 abssum(Wo), y=2 absmax(x), y=3 bias2 ----------
// bias2[m] = (bk . mk[m,:]) / 32  (folded softmax scale), one wave per row.
__global__ __launch_bounds__(256) void stats_kernel(const float* __restrict__ Wk,
                                                    const float* __restrict__ Wo,
                                                    const float* __restrict__ x,
                                                    const float* __restrict__ bk,
                                                    const float* __restrict__ mk,
                                                    float* __restrict__ bias2,
                                                    Scalars* __restrict__ sc) {
  const int which = blockIdx.y;
  size_t tid = (size_t)blockIdx.x * 256 + threadIdx.x;
  size_t stride = (size_t)gridDim.x * 256;
  if (which < 2) {
    const float* w = which ? Wo : Wk;
    const size_t n = 1048576;
    double s = 0.0;
    for (size_t i = tid * 4; i < n; i += stride * 4) {
      float4 v = *(const float4*)(w + i);
      s += (double)fabsf(v.x) + (double)fabsf(v.y) + (double)fabsf(v.z) + (double)fabsf(v.w);
    }
#pragma unroll
    for (int o = 32; o > 0; o >>= 1) s += __shfl_xor(s, o);
    __shared__ double sm[4];
    if ((threadIdx.x & 63) == 0) sm[threadIdx.x >> 6] = s;
    __syncthreads();
    if (threadIdx.x == 0)
      atomicAdd(which ? &sc->sum_wo : &sc->sum_wk, sm[0] + sm[1] + sm[2] + sm[3]);
  } else if (which == 2) {
    const size_t n = (size_t)32768 * 1024;
    float m = 0.0f;
    for (size_t i = tid * 4; i < n; i += stride * 4) {
      float4 v = *(const float4*)(x + i);
      m = fmaxf(m, fmaxf(fmaxf(fabsf(v.x), fabsf(v.y)), fmaxf(fabsf(v.z), fabsf(v.w))));
    }
#pragma unroll
    for (int o = 32; o > 0; o >>= 1) m = fmaxf(m, __shfl_xor(m, o));
    __shared__ float smf[4];
    if ((threadIdx.x & 63) == 0) smf[threadIdx.x >> 6] = m;
    __syncthreads();
    if (threadIdx.x == 0)
      atomicMax(&sc->max_x_bits,
                __float_as_uint(fmaxf(fmaxf(smf[0], smf[1]), fmaxf(smf[2], smf[3]))));
  } else {
    if (blockIdx.x >= 512) return;
    const int l = threadIdx.x & 63, wv = threadIdx.x >> 6;
    const int m = blockIdx.x * 4 + wv;
    float dot = 0.f;
#pragma unroll
    for (int c = 0; c < 4; ++c) {
      float4 b4 = *(const float4*)(bk + c * 256 + l * 4);
      float4 k4 = *(const float4*)(mk + (size_t)m * 1024 + c * 256 + l * 4);
      dot += b4.x * k4.x + b4.y * k4.y + b4.z * k4.z + b4.w * k4.w;
    }
#pragma unroll
    for (int o = 32; o > 0; o >>= 1) dot += __shfl_xor(dot, o);
    if (l == 0) bias2[m] = dot * 0.03125f;
  }
}

// ---- prep: y=0 transpose-quant Wk -> qWkT bf16 (+-1/0), y=1 quantW(Wo) i8,
//      y=2 cast(mk), y=3 transpose(mv), y=4 quant x -> bf16 ints ---------------
__global__ __launch_bounds__(256) void prep_kernel(
    const float* __restrict__ Wk, const float* __restrict__ Wo,
    const float* __restrict__ mk, const float* __restrict__ mv,
    const float* __restrict__ x, __hip_bfloat16* __restrict__ qWkT,
    char* __restrict__ qWo8, __hip_bfloat16* __restrict__ mkb,
    __hip_bfloat16* __restrict__ mvT, __hip_bfloat16* __restrict__ qxb,
    const Scalars* __restrict__ sc) {
  __shared__ float tl[32][33];
  const int which = blockIdx.y;
  const int t = threadIdx.x;
  size_t tid = (size_t)blockIdx.x * 256 + t;
  size_t stride = (size_t)gridDim.x * 256;
  if (which == 0) {
    // Wk [d][i] f32 -> qWkT [i][d] bf16 in {-1,0,1}; 32x32 LDS transpose tiles
    if (blockIdx.x >= 1024) return;
    const float thr = 0.5f * (float)(sc->sum_wk * (1.0 / 1048576.0));
    const int ti = blockIdx.x & 31;   // i-block
    const int tj = blockIdx.x >> 5;   // d-block
    const int tx = t & 31, ty = t >> 5;
#pragma unroll
    for (int r = 0; r < 4; ++r)
      tl[ty + r * 8][tx] = Wk[(size_t)(tj * 32 + ty + r * 8) * 1024 + ti * 32 + tx];
    __syncthreads();
#pragma unroll
    for (int r = 0; r < 4; ++r) {
      float v = tl[tx][ty + r * 8];
      float q = fabsf(v) > thr ? (v > 0.f ? 1.f : -1.f) : 0.f;
      qWkT[(size_t)(ti * 32 + ty + r * 8) * 1024 + tj * 32 + tx] = __float2bfloat16(q);
    }
  } else if (which == 1) {
    const double sum = sc->sum_wo;
    const float thr = 0.5f * (float)(sum * (1.0 / 1048576.0));
    const size_t n = 1048576;
    for (size_t i = tid * 4; i < n; i += stride * 4) {
      float4 v = *(const float4*)(Wo + i);
      char4 o;
      o.x = (char)(fabsf(v.x) > thr ? (v.x > 0.f ? 1 : -1) : 0);
      o.y = (char)(fabsf(v.y) > thr ? (v.y > 0.f ? 1 : -1) : 0);
      o.z = (char)(fabsf(v.z) > thr ? (v.z > 0.f ? 1 : -1) : 0);
      o.w = (char)(fabsf(v.w) > thr ? (v.w > 0.f ? 1 : -1) : 0);
      *(char4*)(qWo8 + i) = o;
    }
  } else if (which == 2) {
    const size_t n = (size_t)2048 * 1024;
    for (size_t i = tid * 4; i < n; i += stride * 4) {
      float4 v = *(const float4*)(mk + i);
      ushort4 o;
      o.x = f2bf(v.x); o.y = f2bf(v.y); o.z = f2bf(v.z); o.w = f2bf(v.w);
      *(ushort4*)((unsigned short*)mkb + i) = o;
    }
  } else if (which == 3) {
    // mv [2048][1024] f32 -> mvT [1024][2048] bf16
    const int ti = blockIdx.x & 31;  // e-block (1024/32)
    const int tj = blockIdx.x >> 5;  // m-block (2048/32)
    const int tx = t & 31, ty = t >> 5;
#pragma unroll
    for (int r = 0; r < 4; ++r)
      tl[ty + r * 8][tx] = mv[(size_t)(tj * 32 + ty + r * 8) * 1024 + ti * 32 + tx];
    __syncthreads();
#pragma unroll
    for (int r = 0; r < 4; ++r)
      mvT[(size_t)(ti * 32 + ty + r * 8) * 2048 + tj * 32 + tx] =
          __float2bfloat16(tl[tx][ty + r * 8]);
  } else {
    // quantize x to i8 grid, store as bf16 (integers <=128 are exact in bf16)
    const float isc = __uint_as_float(sc->max_x_bits) / 127.0f;
    const size_t n = (size_t)32768 * 1024;
    for (size_t i = tid * 4; i < n; i += stride * 4) {
      float4 v = *(const float4*)(x + i);
      ushort4 o;
      o.x = f2bf(fminf(fmaxf(rintf(v.x / isc), -128.f), 127.f));
      o.y = f2bf(fminf(fmaxf(rintf(v.y / isc), -128.f), 127.f));
      o.z = f2bf(fminf(fmaxf(rintf(v.z / isc), -128.f), 127.f));
      o.w = f2bf(fminf(fmaxf(rintf(v.w / isc), -128.f), 127.f));
      *(ushort4*)((unsigned short*)qxb + i) = o;
    }
  }
}

// ------- quantize y (bf16 storage) -> i8; isc from exact f32 absmax ------------
__global__ __launch_bounds__(256) void quant_act_bf16_kernel(
    const __hip_bfloat16* __restrict__ y, char* __restrict__ q,
    const unsigned int* __restrict__ maxbits, size_t n) {
  const float isc = __uint_as_float(*maxbits) / 127.0f;
  size_t tid = (size_t)blockIdx.x * blockDim.x + threadIdx.x;
  size_t stride = (size_t)gridDim.x * blockDim.x;
  for (size_t i = tid * 8; i < n; i += stride * 8) {
    uint4 r = *(const uint4*)((const unsigned short*)y + i);
    float v[8];
    v[0] = __uint_as_float(r.x << 16); v[1] = __uint_as_float(r.x & 0xffff0000u);
    v[2] = __uint_as_float(r.y << 16); v[3] = __uint_as_float(r.y & 0xffff0000u);
    v[4] = __uint_as_float(r.z << 16); v[5] = __uint_as_float(r.z & 0xffff0000u);
    v[6] = __uint_as_float(r.w << 16); v[7] = __uint_as_float(r.w & 0xffff0000u);
    char o[8];
#pragma unroll
    for (int j = 0; j < 8; ++j)
      o[j] = (char)(int)fminf(fmaxf(rintf(v[j] / isc), -128.f), 127.f);
    uint2 pk;
    pk.x = (unsigned char)o[0] | ((unsigned)(unsigned char)o[1] << 8) |
           ((unsigned)(unsigned char)o[2] << 16) | ((unsigned)(unsigned char)o[3] << 24);
    pk.y = (unsigned char)o[4] | ((unsigned)(unsigned char)o[5] << 8) |
           ((unsigned)(unsigned char)o[6] << 16) | ((unsigned)(unsigned char)o[7] << 24);
    *(uint2*)(q + i) = pk;
  }
}

// ------- softmax, rows of 2048, in-place bf16; one wave per row (no LDS) -------
__global__ __launch_bounds__(256) void softmax_kernel(__hip_bfloat16* __restrict__ sims) {
  const int t = threadIdx.x, l = t & 63, wv = t >> 6;
  unsigned short* row = (unsigned short*)(sims + ((size_t)blockIdx.x * 4 + wv) * 2048);
  uint4 r4[4];
  float v[32];
#pragma unroll
  for (int c = 0; c < 4; ++c) r4[c] = *(const uint4*)(row + c * 512 + l * 8);
#pragma unroll
  for (int c = 0; c < 4; ++c) {
    unsigned u0 = r4[c].x, u1 = r4[c].y, u2 = r4[c].z, u3 = r4[c].w;
    v[c * 8 + 0] = __uint_as_float(u0 << 16); v[c * 8 + 1] = __uint_as_float(u0 & 0xffff0000u);
    v[c * 8 + 2] = __uint_as_float(u1 << 16); v[c * 8 + 3] = __uint_as_float(u1 & 0xffff0000u);
    v[c * 8 + 4] = __uint_as_float(u2 << 16); v[c * 8 + 5] = __uint_as_float(u2 & 0xffff0000u);
    v[c * 8 + 6] = __uint_as_float(u3 << 16); v[c * 8 + 7] = __uint_as_float(u3 & 0xffff0000u);
  }
  float m = v[0];
#pragma unroll
  for (int i = 1; i < 32; ++i) m = fmaxf(m, v[i]);
#pragma unroll
  for (int o = 32; o > 0; o >>= 1) m = fmaxf(m, __shfl_xor(m, o));
  float s = 0.f;
#pragma unroll
  for (int i = 0; i < 32; ++i) { v[i] = expf(v[i] - m); s += v[i]; }
#pragma unroll
  for (int o = 32; o > 0; o >>= 1) s += __shfl_xor(s, o);
#pragma unroll
  for (int c = 0; c < 4; ++c) {
    unsigned short b[8];
#pragma unroll
    for (int j = 0; j < 8; ++j) b[j] = f2bf(v[c * 8 + j] / s);
    uint4 o4;
    o4.x = (unsigned)b[0] | ((unsigned)b[1] << 16);
    o4.y = (unsigned)b[2] | ((unsigned)b[3] << 16);
    o4.z = (unsigned)b[4] | ((unsigned)b[5] << 16);
    o4.w = (unsigned)b[6] | ((unsigned)b[7] << 16);
    *(uint4*)(row + c * 512 + l * 8) = o4;
  }
}

// ---------------- unified 256x256 NT MFMA GEMM (R2 schedule, best measured) ----
// C[m,n] = sum_k A[m,k]*B[n,k], 128-byte K-tiles (bf16 BK=64 elems / i8 BK=128).
// 512 threads = 8 waves (2M x 4N); per-wave output 128x64.
// EPI: 1=bf16(acc + aux[col])            (sims; scale folded into B=K2')
//      2=bf16(acc+aux[row,col]) + f32 absmax -> max_y   (y path)
//      4=f32(acc*sO+aux[col])            (i8 out GEMM)
//      5=bf16(acc * s_k/32)              (K2' build)
#define CFENCE() asm volatile("" ::: "memory")
#define BAR8() { CFENCE(); __builtin_amdgcn_s_barrier(); CFENCE(); }
#define WLGKM(N) { asm volatile("s_waitcnt lgkmcnt(" #N ")" ::: "memory"); __builtin_amdgcn_sched_barrier(0); }
#define WVM(N) asm volatile("s_waitcnt vmcnt(" #N ")" ::: "memory")

template <int EPI>
__global__ __launch_bounds__(512, 2) void gemm8(
    const char* __restrict__ A, const char* __restrict__ B, void* __restrict__ C,
    const float* __restrict__ aux, Scalars* __restrict__ sc,
    int Ndim, int KB, int nxShift) {
  constexpr bool I8 = (EPI == 4);
  using FR  = typename std::conditional<I8, i32x4, bf16x8>::type;
  using ACC = typename std::conditional<I8, i32x4, f32x4>::type;
  __shared__ __align__(16) char lds[4][2][16384];  // [A0,A1,B0,B1][slot][16KiB]

  int bx, by;
  tile_swizzle(nxShift, bx, by);
  const int rowBlk = by * 256, colBlk = bx * 256;

  const int t = threadIdx.x, w = t >> 6, l = t & 63;
  const int wm = w >> 2, wn = w & 3;
  const int quad = l >> 4, m16 = l & 15;
  const int NT = KB >> 7, NIT = NT >> 1;

  int voA[2][2], voB[2][2];
#pragma unroll
  for (int hf = 0; hf < 2; ++hf)
#pragma unroll
    for (int j = 0; j < 2; ++j) {
      const int idx = j * 64 + (t >> 3);
      const int kby = ((t & 7) ^ (idx & 7)) << 4;
      voA[hf][j] = (rowBlk + ((idx >> 6) << 7) + (hf << 6) + (idx & 63)) * KB + kby;
      voB[hf][j] = (colBlk + ((idx >> 5) << 6) + (hf << 5) + (idx & 31)) * KB + kby;
    }

  const char* baA[2];
  const char* baB[2];
#pragma unroll
  for (int ks = 0; ks < 2; ++ks) {
    const int x16 = ((ks << 6) + (quad << 4)) ^ ((m16 & 7) << 4);
    baA[ks] = &lds[0][0][(wm * 64 + m16) * 128 + x16];
    baB[ks] = &lds[2][0][(wn * 32 + m16) * 128 + x16];
  }

#define STG_A(slot, hf, tk)                                                         \
  if ((tk) < NT) {                                                                  \
    _Pragma("unroll") for (int j = 0; j < 2; ++j)                                   \
      async16(&lds[hf][slot][j * 8192 + (w << 10)],                                 \
              A + (((size_t)(tk)) << 7) + voA[hf][j]);                              \
  }
#define STG_B(slot, hf, tk)                                                         \
  if ((tk) < NT) {                                                                  \
    _Pragma("unroll") for (int j = 0; j < 2; ++j)                                   \
      async16(&lds[2 + (hf)][slot][j * 8192 + (w << 10)],                           \
              B + (((size_t)(tk)) << 7) + voB[hf][j]);                              \
  }

#define LD_A(dst, slot, hf, f, ks) \
  dst = *(const FR*)(baA[ks] + ((hf)*32768 + (slot)*16384 + (f)*2048));
#define LD_B(dst, slot, hf, gg, ks) \
  dst = *(const FR*)(baB[ks] + ((hf)*32768 + (slot)*16384 + (gg)*2048));

#define R_A0(s) { _Pragma("unroll") for (int f_ = 0; f_ < 4; ++f_) { LD_A(af[f_][0], s, 0, f_, 0); LD_A(af[f_][1], s, 0, f_, 1); } }
#define R_A1(s) { _Pragma("unroll") for (int f_ = 0; f_ < 4; ++f_) { LD_A(af[f_][0], s, 1, f_, 0); LD_A(af[f_][1], s, 1, f_, 1); } }
#define R_B0(s) { _Pragma("unroll") for (int g_ = 0; g_ < 2; ++g_) { LD_B(b0[g_][0], s, 0, g_, 0); LD_B(b0[g_][1], s, 0, g_, 1); } }
#define R_B1(s) { _Pragma("unroll") for (int g_ = 0; g_ < 2; ++g_) { LD_B(b1[g_][0], s, 1, g_, 0); LD_B(b1[g_][1], s, 1, g_, 1); } }

#define MM8(FO, GO, BR)                                                             \
  __builtin_amdgcn_s_setprio(1);                                                    \
  _Pragma("unroll") for (int f_ = 0; f_ < 4; ++f_)                                  \
    _Pragma("unroll") for (int g_ = 0; g_ < 2; ++g_) {                              \
      acc[(FO) + f_][(GO) + g_] = mm(af[f_][0], BR[g_][0], acc[(FO) + f_][(GO) + g_]); \
      acc[(FO) + f_][(GO) + g_] = mm(af[f_][1], BR[g_][1], acc[(FO) + f_][(GO) + g_]); \
    }                                                                               \
  __builtin_amdgcn_s_setprio(0);

#define TSTEP(s, tk, last)                                                          \
  {                                                                                 \
    R_B1(s);                                                                        \
    STG_A((s) ^ 1, 1, (tk) + 1);                                                    \
    BAR8(); WLGKM(4);                                                               \
    MM8(0, 0, b0);                                                                  \
    BAR8();                                                                         \
    STG_A(s, 0, (tk) + 2);                                                          \
    BAR8(); WLGKM(0);                                                               \
    MM8(0, 2, b1);                                                                  \
    R_A1(s);                                                                        \
    BAR8();                                                                         \
    STG_B(s, 0, (tk) + 2);                                                          \
    BAR8(); WLGKM(0);                                                               \
    MM8(4, 0, b0);                                                                  \
    BAR8();                                                                         \
    STG_B(s, 1, (tk) + 2);                                                          \
    if (last) { WVM(0); } else { WVM(6); }                                          \
    BAR8();                                                                         \
    MM8(4, 2, b1);                                                                  \
    R_A0((s) ^ 1);                                                                  \
    R_B0((s) ^ 1);                                                                  \
  }

  FR af[4][2], b0[2][2], b1[2][2];
  ACC acc[8][4] = {};

  STG_A(0, 0, 0); STG_B(0, 0, 0); STG_B(0, 1, 0); STG_A(0, 1, 0);
  CFENCE();
  STG_A(1, 0, 1); STG_B(1, 0, 1); STG_B(1, 1, 1);
  WVM(6);
  BAR8();
  R_A0(0); R_B0(0);

  for (int it = 0; it < NIT; ++it) {
    const bool last = (it == NIT - 1);
    TSTEP(0, it * 2, last);
    TSTEP(1, it * 2 + 1, last);
  }

  float sK = 0.0f;
  if constexpr (EPI == 5)
    sK = (float)(sc->sum_wk * (1.0 / 1048576.0)) *
         (__uint_as_float(sc->max_x_bits) / 127.0f) * 0.03125f;
  if constexpr (EPI == 4)
    sK = (float)(sc->sum_wo * (1.0 / 1048576.0)) * (__uint_as_float(sc->max_y_bits) / 127.0f);

  float amax = 0.0f;
#pragma unroll
  for (int f = 0; f < 8; ++f) {
#pragma unroll
    for (int g = 0; g < 4; ++g) {
      const int col = colBlk + wn * 64 + g * 16 + m16;
#pragma unroll
      for (int rg = 0; rg < 4; ++rg) {
        const int row = rowBlk + wm * 128 + f * 16 + quad * 4 + rg;
        if constexpr (EPI == 1) {
          ((__hip_bfloat16*)C)[(size_t)row * Ndim + col] =
              __float2bfloat16(acc[f][g][rg] + aux[col]);
        } else if constexpr (EPI == 2) {
          float v = acc[f][g][rg] + aux[(size_t)row * Ndim + col];
          ((__hip_bfloat16*)C)[(size_t)row * Ndim + col] = __float2bfloat16(v);
          amax = fmaxf(amax, fabsf(v));
        } else if constexpr (EPI == 5) {
          ((__hip_bfloat16*)C)[(size_t)row * Ndim + col] =
              __float2bfloat16(acc[f][g][rg] * sK);
        } else {
          ((float*)C)[(size_t)row * Ndim + col] = (float)acc[f][g][rg] * sK + aux[col];
        }
      }
    }
  }

  if constexpr (EPI == 2) {
#pragma unroll
    for (int o = 32; o > 0; o >>= 1) amax = fmaxf(amax, __shfl_xor(amax, o));
    if (l == 0) atomicMax(&sc->max_y_bits, __float_as_uint(amax));
  }
#undef STG_A
#undef STG_B
#undef LD_A
#undef LD_B
#undef R_A0
#undef R_A1
#undef R_B0
#undef R_B1
#undef MM8
#undef TSTEP
}

extern "C" void kernel_launch(void* const* d_in, const int* in_sizes, int n_in,
                              void* d_out, int out_size, void* d_ws, size_t ws_size,
                              hipStream_t stream) {
  (void)in_sizes; (void)n_in; (void)out_size; (void)ws_size;
  const float* x  = (const float*)d_in[0];   // [8,4096,1024]
  const float* mk = (const float*)d_in[1];   // [2048,1024]
  const float* mv = (const float*)d_in[2];   // [2048,1024]
  const float* Wk = (const float*)d_in[3];   // [1024,1024]
  const float* bk = (const float*)d_in[4];   // [1024]
  // d_in[5], d_in[6] = Wv, bv -> dead w.r.t. output; skipped.
  const float* Wo = (const float*)d_in[7];
  const float* bo = (const float*)d_in[8];
  float* out = (float*)d_out;

  const int M = 32768, E = 1024, MEM = 2048;

  char* ws = (char*)d_ws;
  Scalars* sc = (Scalars*)ws;
  const size_t off0 = 256;
  __hip_bfloat16* qxb = (__hip_bfloat16*)(ws + off0);                 // 64 MB
  __hip_bfloat16* yb  = (__hip_bfloat16*)(ws + off0);                 // 64 MB (reuses qxb; qxb dead after GEMM1)
  const size_t off1 = off0 + (size_t)M * E * 2;
  __hip_bfloat16* sims = (__hip_bfloat16*)(ws + off1);                // 128 MB
  char* qy8 = (char*)sims;                                            // reuses sims (32 MB)
  const size_t off2 = off1 + (size_t)M * MEM * 2;
  __hip_bfloat16* qWkT = (__hip_bfloat16*)(ws + off2);                // 2 MB
  char* qWo8 = (char*)(qWkT + (size_t)E * E);                         // 1 MB
  __hip_bfloat16* mkb = (__hip_bfloat16*)(qWo8 + (size_t)E * E);      // 4 MB
  __hip_bfloat16* mvT = mkb + (size_t)MEM * E;                        // 4 MB
  __hip_bfloat16* K2b = mvT + (size_t)E * MEM;                        // 4 MB
  float* bias2 = (float*)(K2b + (size_t)MEM * E);                     // 8 KB

  hipMemsetAsync(ws, 0, 256, stream);

  // stats: abssum(Wk), abssum(Wo), absmax(x), bias2 = (bk . mk)/32
  stats_kernel<<<dim3(1024, 4), dim3(256), 0, stream>>>(Wk, Wo, x, bk, mk, bias2, sc);
  // prep: transpose-quant Wk->qWkT(bf16), quantW(Wo), cast(mk), transpose(mv),
  //       quant x -> bf16-integer grid
  prep_kernel<<<dim3(2048, 5), dim3(256), 0, stream>>>(Wk, Wo, mk, mv, x, qWkT, qWo8,
                                                       mkb, mvT, qxb, sc);

  // K2' = bf16( (s_k/32) * (mk @ qWk) )     [bf16, 2048x1024, KB=2048, 32 blocks]
  gemm8<5><<<dim3((E / 256) * (MEM / 256)), dim3(512), 0, stream>>>(
      (const char*)mkb, (const char*)qWkT, K2b, nullptr, sc, E, 2 * E, 2);
  // sims = bf16(qx @ K2'^T + bias2)         [bf16, KB=2048]  (qk GEMM folded away)
  gemm8<1><<<dim3((MEM / 256) * (M / 256)), dim3(512), 0, stream>>>(
      (const char*)qxb, (const char*)K2b, sims, bias2, sc, MEM, 2 * E, 3);
  // softmax rows (in place), one wave per row
  softmax_kernel<<<dim3(M / 4), dim3(256), 0, stream>>>(sims);
  // y = probs @ mv + x (+ global max|y| from exact f32)  [bf16, KB=4096]
  gemm8<2><<<dim3((E / 256) * (M / 256)), dim3(512), 0, stream>>>(
      (const char*)sims, (const char*)mvT, yb, x, sc, E, 2 * MEM, 2);
  // qy = quant(y)  (y read as bf16)
  quant_act_bf16_kernel<<<dim3(2048), dim3(256), 0, stream>>>(yb, qy8, &sc->max_y_bits,
                                                              (size_t)M * E);
  // out = (qy @ qWo^T) * s_o + bo           [i8, KB=1024]
  gemm8<4><<<dim3((E / 256) * (M / 256)), dim3(512), 0, stream>>>(
      (const char*)qy8, (const char*)qWo8, out, bo, sc, E, E, 2);
}

// Round 9
// 727.255 us; speedup vs baseline: 1.0708x; 1.0144x over previous
//
#include <hip/hip_runtime.h>
#include <hip/hip_bf16.h>
#include <stdint.h>
#include <type_traits>

typedef __attribute__((ext_vector_type(8))) short bf16x8;
typedef __attribute__((ext_vector_type(4))) float f32x4;
typedef __attribute__((ext_vector_type(4))) int i32x4;

struct Scalars {
  double sum_wk;            // sum |Wk|
  double sum_wo;            // sum |Wo|
  unsigned int max_x_bits;  // max|x| as uint bits (nonneg float)
  unsigned int max_y_bits;  // max|x+retrieved| as uint bits
};

__device__ __forceinline__ unsigned short f2bf(float f) {
  __hip_bfloat16 h = __float2bfloat16(f);
  return *reinterpret_cast<unsigned short*>(&h);
}

// async global->LDS, 16B per lane; LDS dest is wave-uniform base + lane*16
__device__ __forceinline__ void async16(void* lds, const void* g) {
  __builtin_amdgcn_global_load_lds((__attribute__((address_space(1))) void*)g,
                                   (__attribute__((address_space(3))) void*)lds, 16, 0, 0);
}

// XCD-aware tile swizzle: consecutive blockIdx go round-robin to XCDs (bid%8);
// give each XCD a contiguous run of row-strips, col-blocks innermost.
__device__ __forceinline__ void tile_swizzle(int nxShift, int& bx, int& by) {
  const int per = gridDim.x >> 3;
  const int tile = (blockIdx.x & 7) * per + (blockIdx.x >> 3);
  bx = tile & ((1 << nxShift) - 1);
  by = tile >> nxShift;
}

// MFMA overloads: bf16 (K=32) and i8 (K=64), both 16B operands.
__device__ __forceinline__ f32x4 mm(bf16x8 a, bf16x8 b, f32x4 c) {
  return __builtin_amdgcn_mfma_f32_16x16x32_bf16(a, b, c, 0, 0, 0);
}
__device__ __forceinline__ i32x4 mm(i32x4 a, i32x4 b, i32x4 c) {
  return __builtin_amdgcn_mfma_i32_16x16x64_i8(a, b, c, 0, 0, 0);
}

// ---- stats: y=0 abssum(Wk), y=1 abssum(Wo), y=2 absmax(x), y=3 bias2 ----------
// bias2[m] = (bk . mk[m,:]) / 32  (folded softmax scale), one wave per row.
__global__ __launch_bounds__(256) void stats_kernel(const float* __restrict__ Wk,
                                                    const float* __restrict__ Wo,
                                                    const float* __restrict__ x,
                                                    const float* __restrict__ bk,
                                                    const float* __restrict__ mk,
                                                    float* __restrict__ bias2,
                                                    Scalars* __restrict__ sc) {
  const int which = blockIdx.y;
  size_t tid = (size_t)blockIdx.x * 256 + threadIdx.x;
  size_t stride = (size_t)gridDim.x * 256;
  if (which < 2) {
    const float* w = which ? Wo : Wk;
    const size_t n = 1048576;
    double s = 0.0;
    for (size_t i = tid * 4; i < n; i += stride * 4) {
      float4 v = *(const float4*)(w + i);
      s += (double)fabsf(v.x) + (double)fabsf(v.y) + (double)fabsf(v.z) + (double)fabsf(v.w);
    }
#pragma unroll
    for (int o = 32; o > 0; o >>= 1) s += __shfl_xor(s, o);
    __shared__ double sm[4];
    if ((threadIdx.x & 63) == 0) sm[threadIdx.x >> 6] = s;
    __syncthreads();
    if (threadIdx.x == 0)
      atomicAdd(which ? &sc->sum_wo : &sc->sum_wk, sm[0] + sm[1] + sm[2] + sm[3]);
  } else if (which == 2) {
    const size_t n = (size_t)32768 * 1024;
    float m = 0.0f;
    for (size_t i = tid * 4; i < n; i += stride * 4) {
      float4 v = *(const float4*)(x + i);
      m = fmaxf(m, fmaxf(fmaxf(fabsf(v.x), fabsf(v.y)), fmaxf(fabsf(v.z), fabsf(v.w))));
    }
#pragma unroll
    for (int o = 32; o > 0; o >>= 1) m = fmaxf(m, __shfl_xor(m, o));
    __shared__ float smf[4];
    if ((threadIdx.x & 63) == 0) smf[threadIdx.x >> 6] = m;
    __syncthreads();
    if (threadIdx.x == 0)
      atomicMax(&sc->max_x_bits,
                __float_as_uint(fmaxf(fmaxf(smf[0], smf[1]), fmaxf(smf[2], smf[3]))));
  } else {
    if (blockIdx.x >= 512) return;
    const int l = threadIdx.x & 63, wv = threadIdx.x >> 6;
    const int m = blockIdx.x * 4 + wv;
    float dot = 0.f;
#pragma unroll
    for (int c = 0; c < 4; ++c) {
      float4 b4 = *(const float4*)(bk + c * 256 + l * 4);
      float4 k4 = *(const float4*)(mk + (size_t)m * 1024 + c * 256 + l * 4);
      dot += b4.x * k4.x + b4.y * k4.y + b4.z * k4.z + b4.w * k4.w;
    }
#pragma unroll
    for (int o = 32; o > 0; o >>= 1) dot += __shfl_xor(dot, o);
    if (l == 0) bias2[m] = dot * 0.03125f;
  }
}

// ---- prep: y=0 transpose-quant Wk -> qWkT bf16 (+-1/0), y=1 quantW(Wo) i8,
//      y=2 cast(mk), y=3 transpose(mv), y=4 quant x -> bf16 ints ---------------
__global__ __launch_bounds__(256) void prep_kernel(
    const float* __restrict__ Wk, const float* __restrict__ Wo,
    const float* __restrict__ mk, const float* __restrict__ mv,
    const float* __restrict__ x, __hip_bfloat16* __restrict__ qWkT,
    char* __restrict__ qWo8, __hip_bfloat16* __restrict__ mkb,
    __hip_bfloat16* __restrict__ mvT, __hip_bfloat16* __restrict__ qxb,
    const Scalars* __restrict__ sc) {
  __shared__ float tl[32][33];
  const int which = blockIdx.y;
  const int t = threadIdx.x;
  size_t tid = (size_t)blockIdx.x * 256 + t;
  size_t stride = (size_t)gridDim.x * 256;
  if (which == 0) {
    // Wk [d][i] f32 -> qWkT [i][d] bf16 in {-1,0,1}; 32x32 LDS transpose tiles
    if (blockIdx.x >= 1024) return;
    const float thr = 0.5f * (float)(sc->sum_wk * (1.0 / 1048576.0));
    const int ti = blockIdx.x & 31;   // i-block
    const int tj = blockIdx.x >> 5;   // d-block
    const int tx = t & 31, ty = t >> 5;
#pragma unroll
    for (int r = 0; r < 4; ++r)
      tl[ty + r * 8][tx] = Wk[(size_t)(tj * 32 + ty + r * 8) * 1024 + ti * 32 + tx];
    __syncthreads();
#pragma unroll
    for (int r = 0; r < 4; ++r) {
      float v = tl[tx][ty + r * 8];
      float q = fabsf(v) > thr ? (v > 0.f ? 1.f : -1.f) : 0.f;
      qWkT[(size_t)(ti * 32 + ty + r * 8) * 1024 + tj * 32 + tx] = __float2bfloat16(q);
    }
  } else if (which == 1) {
    const double sum = sc->sum_wo;
    const float thr = 0.5f * (float)(sum * (1.0 / 1048576.0));
    const size_t n = 1048576;
    for (size_t i = tid * 4; i < n; i += stride * 4) {
      float4 v = *(const float4*)(Wo + i);
      char4 o;
      o.x = (char)(fabsf(v.x) > thr ? (v.x > 0.f ? 1 : -1) : 0);
      o.y = (char)(fabsf(v.y) > thr ? (v.y > 0.f ? 1 : -1) : 0);
      o.z = (char)(fabsf(v.z) > thr ? (v.z > 0.f ? 1 : -1) : 0);
      o.w = (char)(fabsf(v.w) > thr ? (v.w > 0.f ? 1 : -1) : 0);
      *(char4*)(qWo8 + i) = o;
    }
  } else if (which == 2) {
    const size_t n = (size_t)2048 * 1024;
    for (size_t i = tid * 4; i < n; i += stride * 4) {
      float4 v = *(const float4*)(mk + i);
      ushort4 o;
      o.x = f2bf(v.x); o.y = f2bf(v.y); o.z = f2bf(v.z); o.w = f2bf(v.w);
      *(ushort4*)((unsigned short*)mkb + i) = o;
    }
  } else if (which == 3) {
    // mv [2048][1024] f32 -> mvT [1024][2048] bf16
    const int ti = blockIdx.x & 31;  // e-block (1024/32)
    const int tj = blockIdx.x >> 5;  // m-block (2048/32)
    const int tx = t & 31, ty = t >> 5;
#pragma unroll
    for (int r = 0; r < 4; ++r)
      tl[ty + r * 8][tx] = mv[(size_t)(tj * 32 + ty + r * 8) * 1024 + ti * 32 + tx];
    __syncthreads();
#pragma unroll
    for (int r = 0; r < 4; ++r)
      mvT[(size_t)(ti * 32 + ty + r * 8) * 2048 + tj * 32 + tx] =
          __float2bfloat16(tl[tx][ty + r * 8]);
  } else {
    // quantize x to i8 grid, store as bf16 (integers <=128 are exact in bf16)
    const float isc = __uint_as_float(sc->max_x_bits) / 127.0f;
    const size_t n = (size_t)32768 * 1024;
    for (size_t i = tid * 4; i < n; i += stride * 4) {
      float4 v = *(const float4*)(x + i);
      ushort4 o;
      o.x = f2bf(fminf(fmaxf(rintf(v.x / isc), -128.f), 127.f));
      o.y = f2bf(fminf(fmaxf(rintf(v.y / isc), -128.f), 127.f));
      o.z = f2bf(fminf(fmaxf(rintf(v.z / isc), -128.f), 127.f));
      o.w = f2bf(fminf(fmaxf(rintf(v.w / isc), -128.f), 127.f));
      *(ushort4*)((unsigned short*)qxb + i) = o;
    }
  }
}

// ------- K2' reduce: K2b = bf16( sK * sum_{p<8} K2f[p] ), sK = s_k*isc_x/32 ----
__global__ __launch_bounds__(256) void k2red_kernel(const float* __restrict__ K2f,
                                                    __hip_bfloat16* __restrict__ K2b,
                                                    const Scalars* __restrict__ sc) {
  const float sK = (float)(sc->sum_wk * (1.0 / 1048576.0)) *
                   (__uint_as_float(sc->max_x_bits) / 127.0f) * 0.03125f;
  const size_t i = ((size_t)blockIdx.x * 256 + threadIdx.x) * 4;  // n = 2M elems
  float4 s = {0.f, 0.f, 0.f, 0.f};
#pragma unroll
  for (int p = 0; p < 8; ++p) {
    float4 v = *(const float4*)(K2f + (size_t)p * 2097152 + i);
    s.x += v.x; s.y += v.y; s.z += v.z; s.w += v.w;
  }
  ushort4 o;
  o.x = f2bf(s.x * sK); o.y = f2bf(s.y * sK); o.z = f2bf(s.z * sK); o.w = f2bf(s.w * sK);
  *(ushort4*)((unsigned short*)K2b + i) = o;
}

// ------- quantize y (bf16 storage) -> i8; isc from exact f32 absmax ------------
__global__ __launch_bounds__(256) void quant_act_bf16_kernel(
    const __hip_bfloat16* __restrict__ y, char* __restrict__ q,
    const unsigned int* __restrict__ maxbits, size_t n) {
  const float isc = __uint_as_float(*maxbits) / 127.0f;
  size_t tid = (size_t)blockIdx.x * blockDim.x + threadIdx.x;
  size_t stride = (size_t)gridDim.x * blockDim.x;
  for (size_t i = tid * 8; i < n; i += stride * 8) {
    uint4 r = *(const uint4*)((const unsigned short*)y + i);
    float v[8];
    v[0] = __uint_as_float(r.x << 16); v[1] = __uint_as_float(r.x & 0xffff0000u);
    v[2] = __uint_as_float(r.y << 16); v[3] = __uint_as_float(r.y & 0xffff0000u);
    v[4] = __uint_as_float(r.z << 16); v[5] = __uint_as_float(r.z & 0xffff0000u);
    v[6] = __uint_as_float(r.w << 16); v[7] = __uint_as_float(r.w & 0xffff0000u);
    char o[8];
#pragma unroll
    for (int j = 0; j < 8; ++j)
      o[j] = (char)(int)fminf(fmaxf(rintf(v[j] / isc), -128.f), 127.f);
    uint2 pk;
    pk.x = (unsigned char)o[0] | ((unsigned)(unsigned char)o[1] << 8) |
           ((unsigned)(unsigned char)o[2] << 16) | ((unsigned)(unsigned char)o[3] << 24);
    pk.y = (unsigned char)o[4] | ((unsigned)(unsigned char)o[5] << 8) |
           ((unsigned)(unsigned char)o[6] << 16) | ((unsigned)(unsigned char)o[7] << 24);
    *(uint2*)(q + i) = pk;
  }
}

// ------- softmax, rows of 2048, in-place bf16; one wave per row (no LDS) -------
__global__ __launch_bounds__(256) void softmax_kernel(__hip_bfloat16* __restrict__ sims) {
  const int t = threadIdx.x, l = t & 63, wv = t >> 6;
  unsigned short* row = (unsigned short*)(sims + ((size_t)blockIdx.x * 4 + wv) * 2048);
  uint4 r4[4];
  float v[32];
#pragma unroll
  for (int c = 0; c < 4; ++c) r4[c] = *(const uint4*)(row + c * 512 + l * 8);
#pragma unroll
  for (int c = 0; c < 4; ++c) {
    unsigned u0 = r4[c].x, u1 = r4[c].y, u2 = r4[c].z, u3 = r4[c].w;
    v[c * 8 + 0] = __uint_as_float(u0 << 16); v[c * 8 + 1] = __uint_as_float(u0 & 0xffff0000u);
    v[c * 8 + 2] = __uint_as_float(u1 << 16); v[c * 8 + 3] = __uint_as_float(u1 & 0xffff0000u);
    v[c * 8 + 4] = __uint_as_float(u2 << 16); v[c * 8 + 5] = __uint_as_float(u2 & 0xffff0000u);
    v[c * 8 + 6] = __uint_as_float(u3 << 16); v[c * 8 + 7] = __uint_as_float(u3 & 0xffff0000u);
  }
  float m = v[0];
#pragma unroll
  for (int i = 1; i < 32; ++i) m = fmaxf(m, v[i]);
#pragma unroll
  for (int o = 32; o > 0; o >>= 1) m = fmaxf(m, __shfl_xor(m, o));
  float s = 0.f;
#pragma unroll
  for (int i = 0; i < 32; ++i) { v[i] = expf(v[i] - m); s += v[i]; }
#pragma unroll
  for (int o = 32; o > 0; o >>= 1) s += __shfl_xor(s, o);
#pragma unroll
  for (int c = 0; c < 4; ++c) {
    unsigned short b[8];
#pragma unroll
    for (int j = 0; j < 8; ++j) b[j] = f2bf(v[c * 8 + j] / s);
    uint4 o4;
    o4.x = (unsigned)b[0] | ((unsigned)b[1] << 16);
    o4.y = (unsigned)b[2] | ((unsigned)b[3] << 16);
    o4.z = (unsigned)b[4] | ((unsigned)b[5] << 16);
    o4.w = (unsigned)b[6] | ((unsigned)b[7] << 16);
    *(uint4*)(row + c * 512 + l * 8) = o4;
  }
}

// ---------------- unified 256x256 NT MFMA GEMM (R2 schedule, best measured) ----
// C[m,n] = sum_k A[m,k]*B[n,k], 128-byte K-tiles (bf16 BK=64 elems / i8 BK=128).
// 512 threads = 8 waves (2M x 4N); per-wave output 128x64.
// EPI: 1=bf16(acc + aux[col])            (sims; scale folded into B=K2')
//      2=bf16(acc+aux[row,col]) + f32 absmax -> max_y   (y path)
//      4=f32(acc*sO+aux[col])            (i8 out GEMM)
//      6=split-K partial: f32 store to slice (K2' build; grid=32 tiles x 8 splits,
//        each split covers a 256-B K-window = 2 K-tiles; no swizzle)
#define CFENCE() asm volatile("" ::: "memory")
#define BAR8() { CFENCE(); __builtin_amdgcn_s_barrier(); CFENCE(); }
#define WLGKM(N) { asm volatile("s_waitcnt lgkmcnt(" #N ")" ::: "memory"); __builtin_amdgcn_sched_barrier(0); }
#define WVM(N) asm volatile("s_waitcnt vmcnt(" #N ")" ::: "memory")

template <int EPI>
__global__ __launch_bounds__(512, 2) void gemm8(
    const char* __restrict__ A, const char* __restrict__ B, void* __restrict__ C,
    const float* __restrict__ aux, Scalars* __restrict__ sc,
    int Ndim, int KB, int nxShift) {
  constexpr bool I8 = (EPI == 4);
  using FR  = typename std::conditional<I8, i32x4, bf16x8>::type;
  using ACC = typename std::conditional<I8, i32x4, f32x4>::type;
  __shared__ __align__(16) char lds[4][2][16384];  // [A0,A1,B0,B1][slot][16KiB]

  int bx, by;
  if constexpr (EPI == 6) {
    const int split = blockIdx.x & 7;
    const int tile = blockIdx.x >> 3;
    bx = tile & 3; by = tile >> 2;
    A += (size_t)split << 8;                       // 256-B K-window offset
    B += (size_t)split << 8;
    C = (void*)((char*)C + ((size_t)split << 23)); // slice = split * 8 MB
  } else {
    tile_swizzle(nxShift, bx, by);
  }
  const int rowBlk = by * 256, colBlk = bx * 256;

  const int t = threadIdx.x, w = t >> 6, l = t & 63;
  const int wm = w >> 2, wn = w & 3;
  const int quad = l >> 4, m16 = l & 15;
  const int NT = (EPI == 6) ? 2 : (KB >> 7);
  const int NIT = NT >> 1;

  int voA[2][2], voB[2][2];
#pragma unroll
  for (int hf = 0; hf < 2; ++hf)
#pragma unroll
    for (int j = 0; j < 2; ++j) {
      const int idx = j * 64 + (t >> 3);
      const int kby = ((t & 7) ^ (idx & 7)) << 4;
      voA[hf][j] = (rowBlk + ((idx >> 6) << 7) + (hf << 6) + (idx & 63)) * KB + kby;
      voB[hf][j] = (colBlk + ((idx >> 5) << 6) + (hf << 5) + (idx & 31)) * KB + kby;
    }

  const char* baA[2];
  const char* baB[2];
#pragma unroll
  for (int ks = 0; ks < 2; ++ks) {
    const int x16 = ((ks << 6) + (quad << 4)) ^ ((m16 & 7) << 4);
    baA[ks] = &lds[0][0][(wm * 64 + m16) * 128 + x16];
    baB[ks] = &lds[2][0][(wn * 32 + m16) * 128 + x16];
  }

#define STG_A(slot, hf, tk)                                                         \
  if ((tk) < NT) {                                                                  \
    _Pragma("unroll") for (int j = 0; j < 2; ++j)                                   \
      async16(&lds[hf][slot][j * 8192 + (w << 10)],                                 \
              A + (((size_t)(tk)) << 7) + voA[hf][j]);                              \
  }
#define STG_B(slot, hf, tk)                                                         \
  if ((tk) < NT) {                                                                  \
    _Pragma("unroll") for (int j = 0; j < 2; ++j)                                   \
      async16(&lds[2 + (hf)][slot][j * 8192 + (w << 10)],                           \
              B + (((size_t)(tk)) << 7) + voB[hf][j]);                              \
  }

#define LD_A(dst, slot, hf, f, ks) \
  dst = *(const FR*)(baA[ks] + ((hf)*32768 + (slot)*16384 + (f)*2048));
#define LD_B(dst, slot, hf, gg, ks) \
  dst = *(const FR*)(baB[ks] + ((hf)*32768 + (slot)*16384 + (gg)*2048));

#define R_A0(s) { _Pragma("unroll") for (int f_ = 0; f_ < 4; ++f_) { LD_A(af[f_][0], s, 0, f_, 0); LD_A(af[f_][1], s, 0, f_, 1); } }
#define R_A1(s) { _Pragma("unroll") for (int f_ = 0; f_ < 4; ++f_) { LD_A(af[f_][0], s, 1, f_, 0); LD_A(af[f_][1], s, 1, f_, 1); } }
#define R_B0(s) { _Pragma("unroll") for (int g_ = 0; g_ < 2; ++g_) { LD_B(b0[g_][0], s, 0, g_, 0); LD_B(b0[g_][1], s, 0, g_, 1); } }
#define R_B1(s) { _Pragma("unroll") for (int g_ = 0; g_ < 2; ++g_) { LD_B(b1[g_][0], s, 1, g_, 0); LD_B(b1[g_][1], s, 1, g_, 1); } }

#define MM8(FO, GO, BR)                                                             \
  __builtin_amdgcn_s_setprio(1);                                                    \
  _Pragma("unroll") for (int f_ = 0; f_ < 4; ++f_)                                  \
    _Pragma("unroll") for (int g_ = 0; g_ < 2; ++g_) {                              \
      acc[(FO) + f_][(GO) + g_] = mm(af[f_][0], BR[g_][0], acc[(FO) + f_][(GO) + g_]); \
      acc[(FO) + f_][(GO) + g_] = mm(af[f_][1], BR[g_][1], acc[(FO) + f_][(GO) + g_]); \
    }                                                                               \
  __builtin_amdgcn_s_setprio(0);

#define TSTEP(s, tk, last)                                                          \
  {                                                                                 \
    R_B1(s);                                                                        \
    STG_A((s) ^ 1, 1, (tk) + 1);                                                    \
    BAR8(); WLGKM(4);                                                               \
    MM8(0, 0, b0);                                                                  \
    BAR8();                                                                         \
    STG_A(s, 0, (tk) + 2);                                                          \
    BAR8(); WLGKM(0);                                                               \
    MM8(0, 2, b1);                                                                  \
    R_A1(s);                                                                        \
    BAR8();                                                                         \
    STG_B(s, 0, (tk) + 2);                                                          \
    BAR8(); WLGKM(0);                                                               \
    MM8(4, 0, b0);                                                                  \
    BAR8();                                                                         \
    STG_B(s, 1, (tk) + 2);                                                          \
    if (last) { WVM(0); } else { WVM(6); }                                          \
    BAR8();                                                                         \
    MM8(4, 2, b1);                                                                  \
    R_A0((s) ^ 1);                                                                  \
    R_B0((s) ^ 1);                                                                  \
  }

  FR af[4][2], b0[2][2], b1[2][2];
  ACC acc[8][4] = {};

  STG_A(0, 0, 0); STG_B(0, 0, 0); STG_B(0, 1, 0); STG_A(0, 1, 0);
  CFENCE();
  STG_A(1, 0, 1); STG_B(1, 0, 1); STG_B(1, 1, 1);
  WVM(6);
  BAR8();
  R_A0(0); R_B0(0);

  for (int it = 0; it < NIT; ++it) {
    const bool last = (it * 2 >= NT - 2);
    TSTEP(0, it * 2, last);
    TSTEP(1, it * 2 + 1, last);
  }

  float sK = 0.0f;
  if constexpr (EPI == 4)
    sK = (float)(sc->sum_wo * (1.0 / 1048576.0)) * (__uint_as_float(sc->max_y_bits) / 127.0f);

  float amax = 0.0f;
#pragma unroll
  for (int f = 0; f < 8; ++f) {
#pragma unroll
    for (int g = 0; g < 4; ++g) {
      const int col = colBlk + wn * 64 + g * 16 + m16;
#pragma unroll
      for (int rg = 0; rg < 4; ++rg) {
        const int row = rowBlk + wm * 128 + f * 16 + quad * 4 + rg;
        if constexpr (EPI == 1) {
          ((__hip_bfloat16*)C)[(size_t)row * Ndim + col] =
              __float2bfloat16(acc[f][g][rg] + aux[col]);
        } else if constexpr (EPI == 2) {
          float v = acc[f][g][rg] + aux[(size_t)row * Ndim + col];
          ((__hip_bfloat16*)C)[(size_t)row * Ndim + col] = __float2bfloat16(v);
          amax = fmaxf(amax, fabsf(v));
        } else if constexpr (EPI == 6) {
          ((float*)C)[(size_t)row * Ndim + col] = acc[f][g][rg];
        } else {
          ((float*)C)[(size_t)row * Ndim + col] = (float)acc[f][g][rg] * sK + aux[col];
        }
      }
    }
  }

  if constexpr (EPI == 2) {
#pragma unroll
    for (int o = 32; o > 0; o >>= 1) amax = fmaxf(amax, __shfl_xor(amax, o));
    if (l == 0) atomicMax(&sc->max_y_bits, __float_as_uint(amax));
  }
#undef STG_A
#undef STG_B
#undef LD_A
#undef LD_B
#undef R_A0
#undef R_A1
#undef R_B0
#undef R_B1
#undef MM8
#undef TSTEP
}

extern "C" void kernel_launch(void* const* d_in, const int* in_sizes, int n_in,
                              void* d_out, int out_size, void* d_ws, size_t ws_size,
                              hipStream_t stream) {
  (void)in_sizes; (void)n_in; (void)out_size; (void)ws_size;
  const float* x  = (const float*)d_in[0];   // [8,4096,1024]
  const float* mk = (const float*)d_in[1];   // [2048,1024]
  const float* mv = (const float*)d_in[2];   // [2048,1024]
  const float* Wk = (const float*)d_in[3];   // [1024,1024]
  const float* bk = (const float*)d_in[4];   // [1024]
  // d_in[5], d_in[6] = Wv, bv -> dead w.r.t. output; skipped.
  const float* Wo = (const float*)d_in[7];
  const float* bo = (const float*)d_in[8];
  float* out = (float*)d_out;

  const int M = 32768, E = 1024, MEM = 2048;

  char* ws = (char*)d_ws;
  Scalars* sc = (Scalars*)ws;
  const size_t off0 = 256;
  __hip_bfloat16* qxb = (__hip_bfloat16*)(ws + off0);                 // 64 MB
  __hip_bfloat16* yb  = (__hip_bfloat16*)(ws + off0);                 // 64 MB (reuses qxb; qxb dead after GEMM1)
  const size_t off1 = off0 + (size_t)M * E * 2;
  __hip_bfloat16* sims = (__hip_bfloat16*)(ws + off1);                // 128 MB
  char* qy8 = (char*)sims;                                            // reuses sims (32 MB)
  const size_t off2 = off1 + (size_t)M * MEM * 2;
  __hip_bfloat16* qWkT = (__hip_bfloat16*)(ws + off2);                // 2 MB
  char* qWo8 = (char*)(qWkT + (size_t)E * E);                         // 1 MB
  __hip_bfloat16* mkb = (__hip_bfloat16*)(qWo8 + (size_t)E * E);      // 4 MB
  __hip_bfloat16* mvT = mkb + (size_t)MEM * E;                        // 4 MB
  __hip_bfloat16* K2b = mvT + (size_t)E * MEM;                        // 4 MB
  float* bias2 = (float*)(K2b + (size_t)MEM * E);                     // 8 KB
  float* K2f = bias2 + 2048;                                          // 64 MB (8 slices x 8 MB)

  hipMemsetAsync(ws, 0, 256, stream);

  // stats: abssum(Wk), abssum(Wo), absmax(x), bias2 = (bk . mk)/32
  stats_kernel<<<dim3(1024, 4), dim3(256), 0, stream>>>(Wk, Wo, x, bk, mk, bias2, sc);
  // prep: transpose-quant Wk->qWkT(bf16), quantW(Wo), cast(mk), transpose(mv),
  //       quant x -> bf16-integer grid
  prep_kernel<<<dim3(2048, 5), dim3(256), 0, stream>>>(Wk, Wo, mk, mv, x, qWkT, qWo8,
                                                       mkb, mvT, qxb, sc);

  // K2' partials: split-K (32 tiles x 8 splits), f32 slices  [bf16 inputs]
  gemm8<6><<<dim3(256), dim3(512), 0, stream>>>(
      (const char*)mkb, (const char*)qWkT, K2f, nullptr, sc, E, 2 * E, 0);
  // K2b = bf16(sK * sum slices)
  k2red_kernel<<<dim3(2048), dim3(256), 0, stream>>>(K2f, K2b, sc);
  // sims = bf16(qx @ K2'^T + bias2)         [bf16, KB=2048]
  gemm8<1><<<dim3((MEM / 256) * (M / 256)), dim3(512), 0, stream>>>(
      (const char*)qxb, (const char*)K2b, sims, bias2, sc, MEM, 2 * E, 3);
  // softmax rows (in place), one wave per row
  softmax_kernel<<<dim3(M / 4), dim3(256), 0, stream>>>(sims);
  // y = probs @ mv + x (+ global max|y| from exact f32)  [bf16, KB=4096]
  gemm8<2><<<dim3((E / 256) * (M / 256)), dim3(512), 0, stream>>>(
      (const char*)sims, (const char*)mvT, yb, x, sc, E, 2 * MEM, 2);
  // qy = quant(y)  (y read as bf16)
  quant_act_bf16_kernel<<<dim3(2048), dim3(256), 0, stream>>>(yb, qy8, &sc->max_y_bits,
                                                              (size_t)M * E);
  // out = (qy @ qWo^T) * s_o + bo           [i8, KB=1024]
  gemm8<4><<<dim3((E / 256) * (M / 256)), dim3(512), 0, stream>>>(
      (const char*)qy8, (const char*)qWo8, out, bo, sc, E, E, 2);
}